// Round 1
// baseline (311.393 us; speedup 1.0000x reference)
//
#include <hip/hip_runtime.h>

typedef _Float16 f16;
typedef _Float16 half8 __attribute__((ext_vector_type(8)));
typedef _Float16 half4v __attribute__((ext_vector_type(4)));
typedef float f32x4 __attribute__((ext_vector_type(4)));

#define MFMA16(a,b,c) __builtin_amdgcn_mfma_f32_16x16x32_f16((a),(b),(c),0,0,0)

// ---------------- cast fp32 -> fp16 (vectorized) ----------------
__global__ void cast_f32_to_f16(const float* __restrict__ in, f16* __restrict__ out, int n4) {
    int i = blockIdx.x * blockDim.x + threadIdx.x;
    if (i < n4) {
        float4 v = ((const float4*)in)[i];
        half4v h;
        h.x = (f16)v.x; h.y = (f16)v.y; h.z = (f16)v.z; h.w = (f16)v.w;
        ((half4v*)out)[i] = h;
    }
}

// ---------------- transpose + cast: in[K][N] fp32 -> out[N][K] fp16 ----------------
__global__ void transpose_cast(const float* __restrict__ in, f16* __restrict__ out, int K, int N) {
    __shared__ f16 tile[32][33];
    int n0 = blockIdx.x * 32, k0 = blockIdx.y * 32;
    int tx = threadIdx.x & 31, ty = threadIdx.x >> 5;   // 256 threads = 32x8
    for (int r = ty; r < 32; r += 8)
        tile[r][tx] = (f16)in[(size_t)(k0 + r) * N + (n0 + tx)];
    __syncthreads();
    for (int r = ty; r < 32; r += 8)
        out[(size_t)(n0 + r) * K + (k0 + tx)] = tile[tx][r];
}

// ---------------- GEMM: C[M][N] = A[M][768] * Bt[N][768]^T ----------------
// MODE 0: qkv epilogue -> scatter into q[b,h,n,d], k[b,h,n,d], vT[b,h,d,n] (fp16)
// MODE 1: proj epilogue -> out fp32 + bias
template<int MODE>
__global__ void gemm_bt(const f16* __restrict__ A, const f16* __restrict__ Bt,
                        f16* __restrict__ qbuf, f16* __restrict__ kbuf, f16* __restrict__ vtbuf,
                        float* __restrict__ out, const float* __restrict__ bias)
{
    constexpr int K = 768;
    __shared__ __align__(16) f16 As[128][40];  // +8 pad: 80B row stride -> conflict-free b128
    __shared__ __align__(16) f16 Bs[128][40];
    const int tid  = threadIdx.x;
    const int lane = tid & 63, wave = tid >> 6;
    const int wm = wave >> 1, wn = wave & 1;          // 2x2 waves, 64x64 each
    const int l15 = lane & 15, l4 = lane >> 4;
    const int m0 = blockIdx.y * 128, n0 = blockIdx.x * 128;
    const int srow = tid >> 2;            // 0..63
    const int schunk = (tid & 3) * 8;     // 0,8,16,24

    f32x4 acc[4][4] = {};

    const f16* Aptr = A  + (size_t)(m0 + srow) * K + schunk;
    const f16* Bptr = Bt + (size_t)(n0 + srow) * K + schunk;

    for (int kt = 0; kt < K; kt += 32) {
        half8 ar0 = *(const half8*)(Aptr + kt);
        half8 ar1 = *(const half8*)(Aptr + (size_t)64 * K + kt);
        half8 br0 = *(const half8*)(Bptr + kt);
        half8 br1 = *(const half8*)(Bptr + (size_t)64 * K + kt);
        __syncthreads();
        *(half8*)&As[srow][schunk]      = ar0;
        *(half8*)&As[srow + 64][schunk] = ar1;
        *(half8*)&Bs[srow][schunk]      = br0;
        *(half8*)&Bs[srow + 64][schunk] = br1;
        __syncthreads();
        half8 af[4], bf[4];
        #pragma unroll
        for (int mi = 0; mi < 4; mi++) af[mi] = *(const half8*)&As[wm*64 + mi*16 + l15][l4*8];
        #pragma unroll
        for (int ni = 0; ni < 4; ni++) bf[ni] = *(const half8*)&Bs[wn*64 + ni*16 + l15][l4*8];
        #pragma unroll
        for (int mi = 0; mi < 4; mi++)
            #pragma unroll
            for (int ni = 0; ni < 4; ni++)
                acc[mi][ni] = MFMA16(af[mi], bf[ni], acc[mi][ni]);
    }

    #pragma unroll
    for (int mi = 0; mi < 4; mi++) {
        #pragma unroll
        for (int ni = 0; ni < 4; ni++) {
            #pragma unroll
            for (int r = 0; r < 4; r++) {
                int gm = m0 + wm*64 + mi*16 + l4*4 + r;   // C row
                int gn = n0 + wn*64 + ni*16 + l15;        // C col
                float v = acc[mi][ni][r];
                if (MODE == 0) {
                    int t = gn / 768, rem = gn % 768;
                    int hh = rem >> 6, dd = rem & 63;
                    int bb = gm >> 10, ii = gm & 1023;
                    int bhh = bb * 12 + hh;
                    f16 hv = (f16)v;
                    if (t == 0)      qbuf[((size_t)bhh * 1024 + ii) * 64 + dd] = hv;
                    else if (t == 1) kbuf[((size_t)bhh * 1024 + ii) * 64 + dd] = hv;
                    else             vtbuf[((size_t)bhh * 64 + dd) * 1024 + ii] = hv;
                } else {
                    out[(size_t)gm * 768 + gn] = v + bias[gn];
                }
            }
        }
    }
}

// ---------------- flash attention: per (b,h), 4 waves x 16 queries ----------------
__global__ void attn_kernel(const f16* __restrict__ qbuf, const f16* __restrict__ kbuf,
                            const f16* __restrict__ vtbuf, f16* __restrict__ obuf)
{
    __shared__ __align__(16) char sPall[4 * 2048];  // per-wave 16x64 f16 P tile (swizzled)
    const int tid = threadIdx.x;
    const int lane = tid & 63, wave = tid >> 6;
    char* sP = sPall + wave * 2048;
    const int bh = blockIdx.y;              // 0..95
    const int b = bh / 12, h = bh % 12;
    const int q0 = blockIdx.x * 64 + wave * 16;
    const int l15 = lane & 15, l4 = lane >> 4;

    const f16* Q  = qbuf  + (size_t)bh * 1024 * 64;
    const f16* Kp = kbuf  + (size_t)bh * 1024 * 64;
    const f16* Vt = vtbuf + (size_t)bh * 64 * 1024;

    half8 aq[2];
    aq[0] = *(const half8*)&Q[(q0 + l15) * 64 + 0  + l4 * 8];
    aq[1] = *(const half8*)&Q[(q0 + l15) * 64 + 32 + l4 * 8];

    f32x4 o[4] = {};
    float mr[4], lr[4];
    #pragma unroll
    for (int r = 0; r < 4; r++) { mr[r] = -1e30f; lr[r] = 0.f; }

    const float scale = 0.125f;   // 64^-0.5

    for (int kv = 0; kv < 1024; kv += 64) {
        f32x4 s[4] = {};
        #pragma unroll
        for (int ni = 0; ni < 4; ni++) {
            const f16* kp = &Kp[(size_t)(kv + ni*16 + l15) * 64 + l4 * 8];
            s[ni] = MFMA16(aq[0], *(const half8*)kp,        s[ni]);
            s[ni] = MFMA16(aq[1], *(const half8*)(kp + 32), s[ni]);
        }
        // scale, row-max
        float bm[4];
        #pragma unroll
        for (int ni = 0; ni < 4; ni++)
            #pragma unroll
            for (int r = 0; r < 4; r++) s[ni][r] *= scale;
        #pragma unroll
        for (int r = 0; r < 4; r++) {
            bm[r] = fmaxf(fmaxf(s[0][r], s[1][r]), fmaxf(s[2][r], s[3][r]));
            #pragma unroll
            for (int off = 1; off < 16; off <<= 1)
                bm[r] = fmaxf(bm[r], __shfl_xor(bm[r], off));
        }
        float al[4];
        #pragma unroll
        for (int r = 0; r < 4; r++) {
            float mn = fmaxf(mr[r], bm[r]);
            al[r] = __expf(mr[r] - mn);
            mr[r] = mn;
        }
        float rs[4] = {0.f, 0.f, 0.f, 0.f};
        #pragma unroll
        for (int ni = 0; ni < 4; ni++)
            #pragma unroll
            for (int r = 0; r < 4; r++) {
                float p = __expf(s[ni][r] - mr[r]);
                s[ni][r] = p;
                rs[r] += p;
            }
        #pragma unroll
        for (int r = 0; r < 4; r++) {
            #pragma unroll
            for (int off = 1; off < 16; off <<= 1)
                rs[r] += __shfl_xor(rs[r], off);
            lr[r] = lr[r] * al[r] + rs[r];
        }
        #pragma unroll
        for (int nd = 0; nd < 4; nd++)
            #pragma unroll
            for (int r = 0; r < 4; r++) o[nd][r] *= al[r];
        // P -> LDS (fp16, XOR-swizzled to kill the 128B-stride bank conflict)
        #pragma unroll
        for (int ni = 0; ni < 4; ni++)
            #pragma unroll
            for (int r = 0; r < 4; r++) {
                int row = l4 * 4 + r, col = ni * 16 + l15;
                int byte = (row * 128 + col * 2) ^ ((row & 7) << 4);
                *(f16*)(sP + byte) = (f16)s[ni][r];
            }
        // PV
        #pragma unroll
        for (int kk = 0; kk < 2; kk++) {
            int row = l15, kb = kk * 32 + l4 * 8;
            int byte = (row * 128 + kb * 2) ^ ((row & 7) << 4);
            half8 pa = *(const half8*)(sP + byte);
            #pragma unroll
            for (int nd = 0; nd < 4; nd++) {
                half8 bv = *(const half8*)&Vt[(size_t)(nd*16 + l15) * 1024 + kv + kb];
                o[nd] = MFMA16(pa, bv, o[nd]);
            }
        }
    }

    f16* Op = obuf + (size_t)b * 1024 * 768 + h * 64;
    #pragma unroll
    for (int nd = 0; nd < 4; nd++)
        #pragma unroll
        for (int r = 0; r < 4; r++) {
            int qi = q0 + l4 * 4 + r;
            int d  = nd * 16 + l15;
            Op[(size_t)qi * 768 + d] = (f16)(o[nd][r] / lr[r]);
        }
}

extern "C" void kernel_launch(void* const* d_in, const int* in_sizes, int n_in,
                              void* d_out, int out_size, void* d_ws, size_t ws_size,
                              hipStream_t stream) {
    const float* x      = (const float*)d_in[0];
    const float* w_qkv  = (const float*)d_in[1];
    const float* w_proj = (const float*)d_in[2];
    const float* b_proj = (const float*)d_in[3];
    float* out = (float*)d_out;
    char* ws = (char*)d_ws;

    // workspace layout (bytes)
    f16* x_h      = (f16*)(ws + 0);          // 8192x768      12,582,912
    f16* w_qkv_t  = (f16*)(ws + 12582912);   // 2304x768       3,538,944
    f16* w_proj_t = (f16*)(ws + 16121856);   // 768x768        1,179,648
    f16* qb       = (f16*)(ws + 17301504);   // 96x1024x64    12,582,912
    f16* kb       = (f16*)(ws + 29884416);   // 96x1024x64    12,582,912
    f16* vtb      = (f16*)(ws + 42467328);   // 96x64x1024    12,582,912
    f16* ob       = (f16*)(ws + 55050240);   // 8192x768      12,582,912

    cast_f32_to_f16<<<dim3(6144), dim3(256), 0, stream>>>(x, x_h, 6291456 / 4);
    transpose_cast<<<dim3(2304 / 32, 768 / 32), dim3(256), 0, stream>>>(w_qkv, w_qkv_t, 768, 2304);
    transpose_cast<<<dim3(768 / 32, 768 / 32), dim3(256), 0, stream>>>(w_proj, w_proj_t, 768, 768);
    gemm_bt<0><<<dim3(2304 / 128, 8192 / 128), dim3(256), 0, stream>>>(
        x_h, w_qkv_t, qb, kb, vtb, nullptr, nullptr);
    attn_kernel<<<dim3(1024 / 64, 96), dim3(256), 0, stream>>>(qb, kb, vtb, ob);
    gemm_bt<1><<<dim3(768 / 128, 8192 / 128), dim3(256), 0, stream>>>(
        ob, w_proj_t, nullptr, nullptr, nullptr, out, b_proj);
}

// Round 2
// 305.777 us; speedup vs baseline: 1.0184x; 1.0184x over previous
//
#include <hip/hip_runtime.h>

typedef _Float16 f16;
typedef _Float16 half8 __attribute__((ext_vector_type(8)));
typedef _Float16 half4v __attribute__((ext_vector_type(4)));
typedef float f32x4 __attribute__((ext_vector_type(4)));

#define MFMA16(a,b,c) __builtin_amdgcn_mfma_f32_16x16x32_f16((a),(b),(c),0,0,0)

// ---------------- cast fp32 -> fp16 (vectorized) ----------------
__global__ void cast_f32_to_f16(const float* __restrict__ in, f16* __restrict__ out, int n4) {
    int i = blockIdx.x * blockDim.x + threadIdx.x;
    if (i < n4) {
        float4 v = ((const float4*)in)[i];
        half4v h;
        h.x = (f16)v.x; h.y = (f16)v.y; h.z = (f16)v.z; h.w = (f16)v.w;
        ((half4v*)out)[i] = h;
    }
}

// ---------------- transpose + cast: in[K][N] fp32 -> out[N][K] fp16 ----------------
__global__ void transpose_cast(const float* __restrict__ in, f16* __restrict__ out, int K, int N) {
    __shared__ f16 tile[32][33];
    int n0 = blockIdx.x * 32, k0 = blockIdx.y * 32;
    int tx = threadIdx.x & 31, ty = threadIdx.x >> 5;   // 256 threads = 32x8
    for (int r = ty; r < 32; r += 8)
        tile[r][tx] = (f16)in[(size_t)(k0 + r) * N + (n0 + tx)];
    __syncthreads();
    for (int r = ty; r < 32; r += 8)
        out[(size_t)(n0 + r) * K + (k0 + tx)] = tile[tx][r];
}

// ---------------- GEMM: C[M][N] = A[M][768] * Bt[N][768]^T ----------------
template<int MODE>
__global__ void gemm_bt(const f16* __restrict__ A, const f16* __restrict__ Bt,
                        f16* __restrict__ qbuf, f16* __restrict__ kbuf, f16* __restrict__ vtbuf,
                        float* __restrict__ out, const float* __restrict__ bias)
{
    constexpr int K = 768;
    __shared__ __align__(16) f16 As[128][40];  // +8 pad
    __shared__ __align__(16) f16 Bs[128][40];
    const int tid  = threadIdx.x;
    const int lane = tid & 63, wave = tid >> 6;
    const int wm = wave >> 1, wn = wave & 1;          // 2x2 waves, 64x64 each
    const int l15 = lane & 15, l4 = lane >> 4;
    const int m0 = blockIdx.y * 128, n0 = blockIdx.x * 128;
    const int srow = tid >> 2;            // 0..63
    const int schunk = (tid & 3) * 8;     // 0,8,16,24

    f32x4 acc[4][4] = {};

    const f16* Aptr = A  + (size_t)(m0 + srow) * K + schunk;
    const f16* Bptr = Bt + (size_t)(n0 + srow) * K + schunk;

    for (int kt = 0; kt < K; kt += 32) {
        half8 ar0 = *(const half8*)(Aptr + kt);
        half8 ar1 = *(const half8*)(Aptr + (size_t)64 * K + kt);
        half8 br0 = *(const half8*)(Bptr + kt);
        half8 br1 = *(const half8*)(Bptr + (size_t)64 * K + kt);
        __syncthreads();
        *(half8*)&As[srow][schunk]      = ar0;
        *(half8*)&As[srow + 64][schunk] = ar1;
        *(half8*)&Bs[srow][schunk]      = br0;
        *(half8*)&Bs[srow + 64][schunk] = br1;
        __syncthreads();
        half8 af[4], bf[4];
        #pragma unroll
        for (int mi = 0; mi < 4; mi++) af[mi] = *(const half8*)&As[wm*64 + mi*16 + l15][l4*8];
        #pragma unroll
        for (int ni = 0; ni < 4; ni++) bf[ni] = *(const half8*)&Bs[wn*64 + ni*16 + l15][l4*8];
        #pragma unroll
        for (int mi = 0; mi < 4; mi++)
            #pragma unroll
            for (int ni = 0; ni < 4; ni++)
                acc[mi][ni] = MFMA16(af[mi], bf[ni], acc[mi][ni]);
    }

    #pragma unroll
    for (int mi = 0; mi < 4; mi++) {
        #pragma unroll
        for (int ni = 0; ni < 4; ni++) {
            #pragma unroll
            for (int r = 0; r < 4; r++) {
                int gm = m0 + wm*64 + mi*16 + l4*4 + r;   // C row
                int gn = n0 + wn*64 + ni*16 + l15;        // C col
                float v = acc[mi][ni][r];
                if (MODE == 0) {
                    int t = gn / 768, rem = gn % 768;
                    int hh = rem >> 6, dd = rem & 63;
                    int bb = gm >> 10, ii = gm & 1023;
                    int bhh = bb * 12 + hh;
                    f16 hv = (f16)v;
                    if (t == 0)      qbuf[((size_t)bhh * 1024 + ii) * 64 + dd] = hv;
                    else if (t == 1) kbuf[((size_t)bhh * 1024 + ii) * 64 + dd] = hv;
                    else             vtbuf[((size_t)bhh * 64 + dd) * 1024 + ii] = hv;
                } else {
                    out[(size_t)gm * 768 + gn] = v + bias[gn];
                }
            }
        }
    }
}

// ---------------- flash attention: swapped-QK, per (b,h), 4 waves x 16 queries ----------------
__global__ void attn_kernel(const f16* __restrict__ qbuf, const f16* __restrict__ kbuf,
                            const f16* __restrict__ vtbuf, f16* __restrict__ obuf)
{
    __shared__ __align__(16) char sPall[4 * 2048];  // per-wave 16x64 f16 P tile (swizzled)
    const int tid = threadIdx.x;
    const int lane = tid & 63, wave = tid >> 6;
    char* sP = sPall + wave * 2048;
    const int bh = blockIdx.y;              // 0..95
    const int b = bh / 12, h = bh % 12;
    const int q0 = blockIdx.x * 64 + wave * 16;
    const int l15 = lane & 15, l4 = lane >> 4;

    const f16* Q  = qbuf  + (size_t)bh * 1024 * 64;
    const f16* Kp = kbuf  + (size_t)bh * 1024 * 64;
    const f16* Vt = vtbuf + (size_t)bh * 64 * 1024;

    // Q fragment (B-operand of swapped QK): lane holds Q[q0+l15][l4*8 + h*32 ..]
    half8 aq[2];
    aq[0] = *(const half8*)&Q[(q0 + l15) * 64 + 0  + l4 * 8];
    aq[1] = *(const half8*)&Q[(q0 + l15) * 64 + 32 + l4 * 8];

    // K fragments (A-operand): preload tile 0
    half8 kf[4][2];
    #pragma unroll
    for (int ni = 0; ni < 4; ni++) {
        const f16* kp = &Kp[(size_t)(ni*16 + l15) * 64 + l4 * 8];
        kf[ni][0] = *(const half8*)kp;
        kf[ni][1] = *(const half8*)(kp + 32);
    }

    f32x4 o[4] = {};
    float mrq = -1e30f, lrq = 0.f;          // running max/sum for query l15 (lane-local)
    const float sl = 0.125f * 1.44269504089f;   // scale * log2(e)

    for (int kv = 0; kv < 1024; kv += 64) {
        // issue V loads for this tile (latency hides under QK+softmax)
        half8 vf[4][2];
        #pragma unroll
        for (int nd = 0; nd < 4; nd++)
            #pragma unroll
            for (int kk = 0; kk < 2; kk++)
                vf[nd][kk] = *(const half8*)&Vt[(size_t)(nd*16 + l15) * 1024 + kv + kk*32 + l4*8];

        // swapped QK: St[key][query]; lane holds 16 keys for query l15
        f32x4 st[4];
        #pragma unroll
        for (int ni = 0; ni < 4; ni++) {
            f32x4 z = {0.f, 0.f, 0.f, 0.f};
            z = MFMA16(kf[ni][0], aq[0], z);
            st[ni] = MFMA16(kf[ni][1], aq[1], z);
        }

        // prefetch next K tile (clamped address, branchless)
        int kvn = (kv + 64 < 1024) ? kv + 64 : 0;
        half8 kn[4][2];
        #pragma unroll
        for (int ni = 0; ni < 4; ni++) {
            const f16* kp = &Kp[(size_t)(kvn + ni*16 + l15) * 64 + l4 * 8];
            kn[ni][0] = *(const half8*)kp;
            kn[ni][1] = *(const half8*)(kp + 32);
        }

        // softmax (log2 domain), mostly in-lane
        #pragma unroll
        for (int ni = 0; ni < 4; ni++)
            #pragma unroll
            for (int r = 0; r < 4; r++) st[ni][r] *= sl;
        float m16 = st[0][0];
        #pragma unroll
        for (int ni = 0; ni < 4; ni++)
            #pragma unroll
            for (int r = 0; r < 4; r++) m16 = fmaxf(m16, st[ni][r]);
        m16 = fmaxf(m16, __shfl_xor(m16, 16));
        m16 = fmaxf(m16, __shfl_xor(m16, 32));
        float mnew = fmaxf(mrq, m16);
        float alpha = exp2f(mrq - mnew);
        mrq = mnew;
        float rs = 0.f;
        #pragma unroll
        for (int ni = 0; ni < 4; ni++)
            #pragma unroll
            for (int r = 0; r < 4; r++) {
                float p = exp2f(st[ni][r] - mrq);
                st[ni][r] = p;
                rs += p;
            }
        rs += __shfl_xor(rs, 16);
        rs += __shfl_xor(rs, 32);
        lrq = lrq * alpha + rs;

        // redistribute alpha to O-row owners (O row q = l4*4+r lives in lane q's lrq/alpha)
        float alr[4];
        #pragma unroll
        for (int r = 0; r < 4; r++) alr[r] = __shfl(alpha, l4*4 + r);
        #pragma unroll
        for (int nd = 0; nd < 4; nd++)
            #pragma unroll
            for (int r = 0; r < 4; r++) o[nd][r] *= alr[r];

        // P -> LDS: lane stores P[q=l15][k=ni*16+l4*4 .. +3] as half4 (swizzled)
        #pragma unroll
        for (int ni = 0; ni < 4; ni++) {
            half4v pk;
            #pragma unroll
            for (int r = 0; r < 4; r++) pk[r] = (f16)st[ni][r];
            int byte = (l15 * 128 + (ni*16 + l4*4) * 2) ^ ((l15 & 7) << 4);
            *(half4v*)(sP + byte) = pk;
        }

        // PV: A = P rows (q=l15, keys l4*8..), B = V^T frags
        #pragma unroll
        for (int kk = 0; kk < 2; kk++) {
            int byte = (l15 * 128 + (kk*32 + l4*8) * 2) ^ ((l15 & 7) << 4);
            half8 pa = *(const half8*)(sP + byte);
            #pragma unroll
            for (int nd = 0; nd < 4; nd++)
                o[nd] = MFMA16(pa, vf[nd][kk], o[nd]);
        }

        #pragma unroll
        for (int ni = 0; ni < 4; ni++) {
            kf[ni][0] = kn[ni][0];
            kf[ni][1] = kn[ni][1];
        }
    }

    // epilogue: divide by row-sum (redistribute lrq to row owners)
    float lrr[4];
    #pragma unroll
    for (int r = 0; r < 4; r++) lrr[r] = 1.f / __shfl(lrq, l4*4 + r);

    f16* Op = obuf + (size_t)b * 1024 * 768 + h * 64;
    #pragma unroll
    for (int nd = 0; nd < 4; nd++)
        #pragma unroll
        for (int r = 0; r < 4; r++) {
            int qi = q0 + l4 * 4 + r;
            int d  = nd * 16 + l15;
            Op[(size_t)qi * 768 + d] = (f16)(o[nd][r] * lrr[r]);
        }
}

extern "C" void kernel_launch(void* const* d_in, const int* in_sizes, int n_in,
                              void* d_out, int out_size, void* d_ws, size_t ws_size,
                              hipStream_t stream) {
    const float* x      = (const float*)d_in[0];
    const float* w_qkv  = (const float*)d_in[1];
    const float* w_proj = (const float*)d_in[2];
    const float* b_proj = (const float*)d_in[3];
    float* out = (float*)d_out;
    char* ws = (char*)d_ws;

    // workspace layout (bytes)
    f16* x_h      = (f16*)(ws + 0);          // 8192x768      12,582,912
    f16* w_qkv_t  = (f16*)(ws + 12582912);   // 2304x768       3,538,944
    f16* w_proj_t = (f16*)(ws + 16121856);   // 768x768        1,179,648
    f16* qb       = (f16*)(ws + 17301504);   // 96x1024x64    12,582,912
    f16* kb       = (f16*)(ws + 29884416);   // 96x1024x64    12,582,912
    f16* vtb      = (f16*)(ws + 42467328);   // 96x64x1024    12,582,912
    f16* ob       = (f16*)(ws + 55050240);   // 8192x768      12,582,912

    cast_f32_to_f16<<<dim3(6144), dim3(256), 0, stream>>>(x, x_h, 6291456 / 4);
    transpose_cast<<<dim3(2304 / 32, 768 / 32), dim3(256), 0, stream>>>(w_qkv, w_qkv_t, 768, 2304);
    transpose_cast<<<dim3(768 / 32, 768 / 32), dim3(256), 0, stream>>>(w_proj, w_proj_t, 768, 768);
    gemm_bt<0><<<dim3(2304 / 128, 8192 / 128), dim3(256), 0, stream>>>(
        x_h, w_qkv_t, qb, kb, vtb, nullptr, nullptr);
    attn_kernel<<<dim3(1024 / 64, 96), dim3(256), 0, stream>>>(qb, kb, vtb, ob);
    gemm_bt<1><<<dim3(768 / 128, 8192 / 128), dim3(256), 0, stream>>>(
        ob, w_proj_t, nullptr, nullptr, nullptr, out, b_proj);
}

// Round 3
// 183.251 us; speedup vs baseline: 1.6993x; 1.6686x over previous
//
#include <hip/hip_runtime.h>

typedef _Float16 f16;
typedef _Float16 half8 __attribute__((ext_vector_type(8)));
typedef _Float16 half4v __attribute__((ext_vector_type(4)));
typedef float f32x4 __attribute__((ext_vector_type(4)));

#define MFMA16(a,b,c) __builtin_amdgcn_mfma_f32_16x16x32_f16((a),(b),(c),0,0,0)

__device__ __forceinline__ void gload_lds16(const f16* g, f16* l) {
    __builtin_amdgcn_global_load_lds(
        (const __attribute__((address_space(1))) unsigned int*)g,
        (__attribute__((address_space(3))) unsigned int*)l, 16, 0, 0);
}

// ---------------- cast fp32 -> fp16 (vectorized) ----------------
__global__ void cast_f32_to_f16(const float* __restrict__ in, f16* __restrict__ out, int n4) {
    int i = blockIdx.x * blockDim.x + threadIdx.x;
    if (i < n4) {
        float4 v = ((const float4*)in)[i];
        half4v h;
        h.x = (f16)v.x; h.y = (f16)v.y; h.z = (f16)v.z; h.w = (f16)v.w;
        ((half4v*)out)[i] = h;
    }
}

// ---------------- transpose + cast: in[K][N] fp32 -> out[N][K] fp16 ----------------
__global__ void transpose_cast(const float* __restrict__ in, f16* __restrict__ out, int K, int N) {
    __shared__ f16 tile[32][33];
    int n0 = blockIdx.x * 32, k0 = blockIdx.y * 32;
    int tx = threadIdx.x & 31, ty = threadIdx.x >> 5;   // 256 threads = 32x8
    for (int r = ty; r < 32; r += 8)
        tile[r][tx] = (f16)in[(size_t)(k0 + r) * N + (n0 + tx)];
    __syncthreads();
    for (int r = ty; r < 32; r += 8)
        out[(size_t)(n0 + r) * K + (k0 + tx)] = tile[tx][r];
}

// ---------------- GEMM: C[M][N] = A[M][768] * Bt[N][768]^T ----------------
template<int MODE>
__global__ void gemm_bt(const f16* __restrict__ A, const f16* __restrict__ Bt,
                        f16* __restrict__ qbuf, f16* __restrict__ kbuf, f16* __restrict__ vtbuf,
                        float* __restrict__ out, const float* __restrict__ bias)
{
    constexpr int K = 768;
    __shared__ __align__(16) f16 As[128][40];  // +8 pad
    __shared__ __align__(16) f16 Bs[128][40];
    const int tid  = threadIdx.x;
    const int lane = tid & 63, wave = tid >> 6;
    const int wm = wave >> 1, wn = wave & 1;          // 2x2 waves, 64x64 each
    const int l15 = lane & 15, l4 = lane >> 4;
    const int m0 = blockIdx.y * 128, n0 = blockIdx.x * 128;
    const int srow = tid >> 2;            // 0..63
    const int schunk = (tid & 3) * 8;     // 0,8,16,24

    f32x4 acc[4][4] = {};

    const f16* Aptr = A  + (size_t)(m0 + srow) * K + schunk;
    const f16* Bptr = Bt + (size_t)(n0 + srow) * K + schunk;

    for (int kt = 0; kt < K; kt += 32) {
        half8 ar0 = *(const half8*)(Aptr + kt);
        half8 ar1 = *(const half8*)(Aptr + (size_t)64 * K + kt);
        half8 br0 = *(const half8*)(Bptr + kt);
        half8 br1 = *(const half8*)(Bptr + (size_t)64 * K + kt);
        __syncthreads();
        *(half8*)&As[srow][schunk]      = ar0;
        *(half8*)&As[srow + 64][schunk] = ar1;
        *(half8*)&Bs[srow][schunk]      = br0;
        *(half8*)&Bs[srow + 64][schunk] = br1;
        __syncthreads();
        half8 af[4], bf[4];
        #pragma unroll
        for (int mi = 0; mi < 4; mi++) af[mi] = *(const half8*)&As[wm*64 + mi*16 + l15][l4*8];
        #pragma unroll
        for (int ni = 0; ni < 4; ni++) bf[ni] = *(const half8*)&Bs[wn*64 + ni*16 + l15][l4*8];
        #pragma unroll
        for (int mi = 0; mi < 4; mi++)
            #pragma unroll
            for (int ni = 0; ni < 4; ni++)
                acc[mi][ni] = MFMA16(af[mi], bf[ni], acc[mi][ni]);
    }

    #pragma unroll
    for (int mi = 0; mi < 4; mi++) {
        #pragma unroll
        for (int ni = 0; ni < 4; ni++) {
            #pragma unroll
            for (int r = 0; r < 4; r++) {
                int gm = m0 + wm*64 + mi*16 + l4*4 + r;   // C row
                int gn = n0 + wn*64 + ni*16 + l15;        // C col
                float v = acc[mi][ni][r];
                if (MODE == 0) {
                    int t = gn / 768, rem = gn % 768;
                    int hh = rem >> 6, dd = rem & 63;
                    int bb = gm >> 10, ii = gm & 1023;
                    int bhh = bb * 12 + hh;
                    f16 hv = (f16)v;
                    if (t == 0)      qbuf[((size_t)bhh * 1024 + ii) * 64 + dd] = hv;
                    else if (t == 1) kbuf[((size_t)bhh * 1024 + ii) * 64 + dd] = hv;
                    else             vtbuf[((size_t)bhh * 64 + dd) * 1024 + ii] = hv;
                } else {
                    out[(size_t)gm * 768 + gn] = v + bias[gn];
                }
            }
        }
    }
}

// ---------------- flash attention: LDS-staged K/V (double-buffered), swapped-QK ----------------
// Block = one head, 64 queries; 4 waves x 16 queries. KV tile = 64.
__global__ __launch_bounds__(256, 4)
void attn_kernel(const f16* __restrict__ qbuf, const f16* __restrict__ kbuf,
                 const f16* __restrict__ vtbuf, f16* __restrict__ obuf)
{
    __shared__ __align__(16) f16 Ks[2][4096];   // [buf][64 keys][64 d], XOR-swizzled content
    __shared__ __align__(16) f16 Vs[2][4096];   // [buf][64 d][64 keys], XOR-swizzled content
    __shared__ __align__(16) char sPall[4 * 2048];  // per-wave 16x64 f16 P tile
    const int tid = threadIdx.x;
    const int lane = tid & 63, wave = tid >> 6;
    char* sP = sPall + wave * 2048;
    const int bh = blockIdx.y;              // 0..95
    const int b = bh / 12, h = bh % 12;
    const int q0 = blockIdx.x * 64 + wave * 16;
    const int l15 = lane & 15, l4 = lane >> 4;

    const f16* Q  = qbuf  + (size_t)bh * 65536;
    const f16* Kp = kbuf  + (size_t)bh * 65536;
    const f16* Vt = vtbuf + (size_t)bh * 65536;

    // Q fragment (B-operand of swapped QK)
    half8 aq[2];
    aq[0] = *(const half8*)&Q[(q0 + l15) * 64 + l4 * 8];
    aq[1] = *(const half8*)&Q[(q0 + l15) * 64 + 32 + l4 * 8];

    // staging geometry: wave w stages rows w*16 .. w*16+15 of K tile and V tile.
    // LDS dest is linear (global_load_lds: base + lane*16B); source address is
    // pre-swizzled so LDS[row][c16] = G[row][c16 ^ (row&7)] (16B-slot units).
    const int srow8 = lane >> 3;            // 0..7 (row within 8-row group = row&7)
    const int c16   = (lane & 7) ^ srow8;   // inverse-swizzled source slot

    f32x4 o[4] = {};
    float mrq = -1e30f, lrq = 0.f;
    const float sl = 0.125f * 1.44269504089f;   // scale * log2(e)

    #define STAGE(buf, kv) do {                                                     \
        _Pragma("unroll")                                                           \
        for (int i = 0; i < 2; ++i) {                                               \
            int rbase = wave * 16 + i * 8;                                          \
            int rl = rbase + srow8;                                                 \
            gload_lds16(Kp + (size_t)((kv) + rl) * 64 + c16 * 8, &Ks[buf][rbase * 64]); \
            gload_lds16(Vt + (size_t)rl * 1024 + (kv) + c16 * 8, &Vs[buf][rbase * 64]); \
        }                                                                           \
    } while (0)

    STAGE(0, 0);
    __syncthreads();

    for (int t = 0; t < 16; ++t) {
        const int cur = t & 1;
        if (t < 15) STAGE(cur ^ 1, (t + 1) * 64);   // in flight during compute

        const char* Kb = (const char*)&Ks[cur][0];
        const char* Vb = (const char*)&Vs[cur][0];

        // swapped QK: St[key][query]; lane holds 16 keys for query l15
        f32x4 st[4];
        #pragma unroll
        for (int ni = 0; ni < 4; ni++) {
            int row = ni * 16 + l15;
            int sw = ((row & 7) << 4);
            half8 k0 = *(const half8*)(Kb + row * 128 + ((l4 * 16) ^ sw));
            half8 k1 = *(const half8*)(Kb + row * 128 + ((64 + l4 * 16) ^ sw));
            f32x4 z = {0.f, 0.f, 0.f, 0.f};
            z = MFMA16(k0, aq[0], z);
            st[ni] = MFMA16(k1, aq[1], z);
        }

        // softmax (log2 domain), mostly in-lane
        #pragma unroll
        for (int ni = 0; ni < 4; ni++)
            #pragma unroll
            for (int r = 0; r < 4; r++) st[ni][r] *= sl;
        float m16 = st[0][0];
        #pragma unroll
        for (int ni = 0; ni < 4; ni++)
            #pragma unroll
            for (int r = 0; r < 4; r++) m16 = fmaxf(m16, st[ni][r]);
        m16 = fmaxf(m16, __shfl_xor(m16, 16));
        m16 = fmaxf(m16, __shfl_xor(m16, 32));
        float mnew = fmaxf(mrq, m16);
        float alpha = exp2f(mrq - mnew);
        mrq = mnew;
        float rs = 0.f;
        #pragma unroll
        for (int ni = 0; ni < 4; ni++)
            #pragma unroll
            for (int r = 0; r < 4; r++) {
                float p = exp2f(st[ni][r] - mrq);
                st[ni][r] = p;
                rs += p;
            }
        rs += __shfl_xor(rs, 16);
        rs += __shfl_xor(rs, 32);
        lrq = lrq * alpha + rs;

        // redistribute alpha to O-row owners
        float alr[4];
        #pragma unroll
        for (int r = 0; r < 4; r++) alr[r] = __shfl(alpha, l4*4 + r);
        #pragma unroll
        for (int nd = 0; nd < 4; nd++)
            #pragma unroll
            for (int r = 0; r < 4; r++) o[nd][r] *= alr[r];

        // P -> LDS (swizzled)
        #pragma unroll
        for (int ni = 0; ni < 4; ni++) {
            half4v pk;
            #pragma unroll
            for (int r = 0; r < 4; r++) pk[r] = (f16)st[ni][r];
            int byte = (l15 * 128 + (ni*16 + l4*4) * 2) ^ ((l15 & 7) << 4);
            *(half4v*)(sP + byte) = pk;
        }

        // PV: A = P rows (q=l15), B = V^T frags from LDS
        #pragma unroll
        for (int kk = 0; kk < 2; kk++) {
            int pbyte = (l15 * 128 + (kk*32 + l4*8) * 2) ^ ((l15 & 7) << 4);
            half8 pa = *(const half8*)(sP + pbyte);
            #pragma unroll
            for (int nd = 0; nd < 4; nd++) {
                int row = nd * 16 + l15;
                half8 bv = *(const half8*)(Vb + row * 128 + ((kk*64 + l4*16) ^ ((row & 7) << 4)));
                o[nd] = MFMA16(pa, bv, o[nd]);
            }
        }

        __syncthreads();   // drains vmcnt (staged tile ready) + guards buffer reuse
    }
    #undef STAGE

    // epilogue
    float lrr[4];
    #pragma unroll
    for (int r = 0; r < 4; r++) lrr[r] = 1.f / __shfl(lrq, l4*4 + r);

    f16* Op = obuf + (size_t)b * 1024 * 768 + h * 64;
    #pragma unroll
    for (int nd = 0; nd < 4; nd++)
        #pragma unroll
        for (int r = 0; r < 4; r++) {
            int qi = q0 + l4 * 4 + r;
            int d  = nd * 16 + l15;
            Op[(size_t)qi * 768 + d] = (f16)(o[nd][r] * lrr[r]);
        }
}

extern "C" void kernel_launch(void* const* d_in, const int* in_sizes, int n_in,
                              void* d_out, int out_size, void* d_ws, size_t ws_size,
                              hipStream_t stream) {
    const float* x      = (const float*)d_in[0];
    const float* w_qkv  = (const float*)d_in[1];
    const float* w_proj = (const float*)d_in[2];
    const float* b_proj = (const float*)d_in[3];
    float* out = (float*)d_out;
    char* ws = (char*)d_ws;

    // workspace layout (bytes)
    f16* x_h      = (f16*)(ws + 0);          // 8192x768      12,582,912
    f16* w_qkv_t  = (f16*)(ws + 12582912);   // 2304x768       3,538,944
    f16* w_proj_t = (f16*)(ws + 16121856);   // 768x768        1,179,648
    f16* qb       = (f16*)(ws + 17301504);   // 96x1024x64    12,582,912
    f16* kb       = (f16*)(ws + 29884416);   // 96x1024x64    12,582,912
    f16* vtb      = (f16*)(ws + 42467328);   // 96x64x1024    12,582,912
    f16* ob       = (f16*)(ws + 55050240);   // 8192x768      12,582,912

    cast_f32_to_f16<<<dim3(6144), dim3(256), 0, stream>>>(x, x_h, 6291456 / 4);
    transpose_cast<<<dim3(2304 / 32, 768 / 32), dim3(256), 0, stream>>>(w_qkv, w_qkv_t, 768, 2304);
    transpose_cast<<<dim3(768 / 32, 768 / 32), dim3(256), 0, stream>>>(w_proj, w_proj_t, 768, 768);
    gemm_bt<0><<<dim3(2304 / 128, 8192 / 128), dim3(256), 0, stream>>>(
        x_h, w_qkv_t, qb, kb, vtb, nullptr, nullptr);
    attn_kernel<<<dim3(1024 / 64, 96), dim3(256), 0, stream>>>(qb, kb, vtb, ob);
    gemm_bt<1><<<dim3(768 / 128, 8192 / 128), dim3(256), 0, stream>>>(
        ob, w_proj_t, nullptr, nullptr, nullptr, out, b_proj);
}

// Round 4
// 166.351 us; speedup vs baseline: 1.8719x; 1.1016x over previous
//
#include <hip/hip_runtime.h>

typedef _Float16 f16;
typedef _Float16 half8 __attribute__((ext_vector_type(8)));
typedef _Float16 half4v __attribute__((ext_vector_type(4)));
typedef float f32x4 __attribute__((ext_vector_type(4)));

#define MFMA16(a,b,c) __builtin_amdgcn_mfma_f32_16x16x32_f16((a),(b),(c),0,0,0)

__device__ __forceinline__ void gload_lds16(const f16* g, f16* l) {
    __builtin_amdgcn_global_load_lds(
        (const __attribute__((address_space(1))) unsigned int*)g,
        (__attribute__((address_space(3))) unsigned int*)l, 16, 0, 0);
}

// ---------------- cast fp32 -> fp16 (vectorized) ----------------
__global__ void cast_f32_to_f16(const float* __restrict__ in, f16* __restrict__ out, int n4) {
    int i = blockIdx.x * blockDim.x + threadIdx.x;
    if (i < n4) {
        float4 v = ((const float4*)in)[i];
        half4v h;
        h.x = (f16)v.x; h.y = (f16)v.y; h.z = (f16)v.z; h.w = (f16)v.w;
        ((half4v*)out)[i] = h;
    }
}

// ---------------- transpose + cast: in[K][N] fp32 -> out[N][K] fp16 ----------------
__global__ void transpose_cast(const float* __restrict__ in, f16* __restrict__ out, int K, int N) {
    __shared__ f16 tile[32][33];
    int n0 = blockIdx.x * 32, k0 = blockIdx.y * 32;
    int tx = threadIdx.x & 31, ty = threadIdx.x >> 5;   // 256 threads = 32x8
    for (int r = ty; r < 32; r += 8)
        tile[r][tx] = (f16)in[(size_t)(k0 + r) * N + (n0 + tx)];
    __syncthreads();
    for (int r = ty; r < 32; r += 8)
        out[(size_t)(n0 + r) * K + (k0 + tx)] = tile[tx][r];
}

// ---------------- GEMM: C[M][N] = A[M][768] * Bt[N][768]^T ----------------
// global_load_lds staging, double-buffered LDS, 1 barrier per K-step (BK=32).
template<int MODE>
__global__ __launch_bounds__(256, 4)
void gemm_bt(const f16* __restrict__ A, const f16* __restrict__ Bt,
             f16* __restrict__ qbuf, f16* __restrict__ kbuf, f16* __restrict__ vtbuf,
             float* __restrict__ out, const float* __restrict__ bias)
{
    constexpr int K = 768;
    __shared__ __align__(16) f16 As[2][128 * 32];
    __shared__ __align__(16) f16 Bs[2][128 * 32];
    const int tid  = threadIdx.x;
    const int lane = tid & 63, wave = tid >> 6;
    const int wm = wave >> 1, wn = wave & 1;          // 2x2 waves, 64x64 each
    const int l15 = lane & 15, l4 = lane >> 4;
    const int m0 = blockIdx.y * 128, n0 = blockIdx.x * 128;
    const int srow  = lane >> 2;          // 0..15 row within staging instr
    const int sslot = lane & 3;           // 16B slot within 64B row

    f32x4 acc[4][4] = {};

    // stage one 128x32 tile of A and B into buf (linear LDS, 4 gload/thread)
    #define GSTAGE(buf, kt) do {                                                     \
        _Pragma("unroll")                                                            \
        for (int i = 0; i < 2; ++i) {                                                \
            int rbase = i * 64 + wave * 16;                                          \
            int row = rbase + srow;                                                  \
            gload_lds16(A  + (size_t)(m0 + row) * K + (kt) + sslot * 8, &As[buf][rbase * 32]); \
            gload_lds16(Bt + (size_t)(n0 + row) * K + (kt) + sslot * 8, &Bs[buf][rbase * 32]); \
        }                                                                            \
    } while (0)

    GSTAGE(0, 0);
    __syncthreads();

    for (int t = 0; t < 24; ++t) {
        const int cur = t & 1;
        if (t < 23) GSTAGE(cur ^ 1, (t + 1) * 32);   // in flight during compute
        half8 af[4], bf[4];
        #pragma unroll
        for (int mi = 0; mi < 4; mi++) af[mi] = *(const half8*)&As[cur][(wm*64 + mi*16 + l15) * 32 + l4*8];
        #pragma unroll
        for (int ni = 0; ni < 4; ni++) bf[ni] = *(const half8*)&Bs[cur][(wn*64 + ni*16 + l15) * 32 + l4*8];
        #pragma unroll
        for (int mi = 0; mi < 4; mi++)
            #pragma unroll
            for (int ni = 0; ni < 4; ni++)
                acc[mi][ni] = MFMA16(af[mi], bf[ni], acc[mi][ni]);
        __syncthreads();   // drains vmcnt (next tile ready) + guards buffer reuse
    }
    #undef GSTAGE

    #pragma unroll
    for (int mi = 0; mi < 4; mi++) {
        #pragma unroll
        for (int ni = 0; ni < 4; ni++) {
            #pragma unroll
            for (int r = 0; r < 4; r++) {
                int gm = m0 + wm*64 + mi*16 + l4*4 + r;   // C row
                int gn = n0 + wn*64 + ni*16 + l15;        // C col
                float v = acc[mi][ni][r];
                if (MODE == 0) {
                    int t = gn / 768, rem = gn % 768;
                    int hh = rem >> 6, dd = rem & 63;
                    int bb = gm >> 10, ii = gm & 1023;
                    int bhh = bb * 12 + hh;
                    f16 hv = (f16)v;
                    if (t == 0)      qbuf[((size_t)bhh * 1024 + ii) * 64 + dd] = hv;
                    else if (t == 1) kbuf[((size_t)bhh * 1024 + ii) * 64 + dd] = hv;
                    else             vtbuf[((size_t)bhh * 64 + dd) * 1024 + ii] = hv;
                } else {
                    out[(size_t)gm * 768 + gn] = v + bias[gn];
                }
            }
        }
    }
}

// ---------------- flash attention: LDS-staged K/V (double-buffered), swapped-QK ----------------
// Block = one head, 64 queries; 4 waves x 16 queries. KV tile = 64.
__global__ __launch_bounds__(256, 4)
void attn_kernel(const f16* __restrict__ qbuf, const f16* __restrict__ kbuf,
                 const f16* __restrict__ vtbuf, f16* __restrict__ obuf)
{
    __shared__ __align__(16) f16 Ks[2][4096];   // [buf][64 keys][64 d], XOR-swizzled content
    __shared__ __align__(16) f16 Vs[2][4096];   // [buf][64 d][64 keys], XOR-swizzled content
    __shared__ __align__(16) char sPall[4 * 2048];  // per-wave 16x64 f16 P tile
    const int tid = threadIdx.x;
    const int lane = tid & 63, wave = tid >> 6;
    char* sP = sPall + wave * 2048;
    const int bh = blockIdx.y;              // 0..95
    const int b = bh / 12, h = bh % 12;
    const int q0 = blockIdx.x * 64 + wave * 16;
    const int l15 = lane & 15, l4 = lane >> 4;

    const f16* Q  = qbuf  + (size_t)bh * 65536;
    const f16* Kp = kbuf  + (size_t)bh * 65536;
    const f16* Vt = vtbuf + (size_t)bh * 65536;

    // Q fragment (B-operand of swapped QK), pre-scaled by scale*log2(e)
    const f16 slh = (f16)(0.125f * 1.44269504089f);
    half8 aq[2];
    aq[0] = *(const half8*)&Q[(q0 + l15) * 64 + l4 * 8];
    aq[1] = *(const half8*)&Q[(q0 + l15) * 64 + 32 + l4 * 8];
    #pragma unroll
    for (int j = 0; j < 8; j++) { aq[0][j] *= slh; aq[1][j] *= slh; }

    // staging geometry (pre-swizzled source, linear LDS dest)
    const int srow8 = lane >> 3;            // 0..7 (row within 8-row group = row&7)
    const int c16   = (lane & 7) ^ srow8;   // inverse-swizzled source slot

    f32x4 o[4] = {};
    float mrq = -1e30f, lrq = 0.f;

    #define STAGE(buf, kv) do {                                                     \
        _Pragma("unroll")                                                           \
        for (int i = 0; i < 2; ++i) {                                               \
            int rbase = wave * 16 + i * 8;                                          \
            int rl = rbase + srow8;                                                 \
            gload_lds16(Kp + (size_t)((kv) + rl) * 64 + c16 * 8, &Ks[buf][rbase * 64]); \
            gload_lds16(Vt + (size_t)rl * 1024 + (kv) + c16 * 8, &Vs[buf][rbase * 64]); \
        }                                                                           \
    } while (0)

    STAGE(0, 0);
    __syncthreads();

    for (int t = 0; t < 16; ++t) {
        const int cur = t & 1;
        if (t < 15) STAGE(cur ^ 1, (t + 1) * 64);   // in flight during compute

        const char* Kb = (const char*)&Ks[cur][0];
        const char* Vb = (const char*)&Vs[cur][0];

        // swapped QK: St[key][query] (log2 domain, scale pre-folded into aq)
        f32x4 st[4];
        #pragma unroll
        for (int ni = 0; ni < 4; ni++) {
            int row = ni * 16 + l15;
            int sw = ((row & 7) << 4);
            half8 k0 = *(const half8*)(Kb + row * 128 + ((l4 * 16) ^ sw));
            half8 k1 = *(const half8*)(Kb + row * 128 + ((64 + l4 * 16) ^ sw));
            f32x4 z = {0.f, 0.f, 0.f, 0.f};
            z = MFMA16(k0, aq[0], z);
            st[ni] = MFMA16(k1, aq[1], z);
        }

        // row max (lane holds 16 keys for query l15)
        float m16 = st[0][0];
        #pragma unroll
        for (int ni = 0; ni < 4; ni++)
            #pragma unroll
            for (int r = 0; r < 4; r++) m16 = fmaxf(m16, st[ni][r]);
        m16 = fmaxf(m16, __shfl_xor(m16, 16));
        m16 = fmaxf(m16, __shfl_xor(m16, 32));

        // defer-max (T13): rescale only when max grew by > 11 (log2) for any query
        if (!__all(m16 - mrq <= 11.0f)) {
            float mnew = fmaxf(mrq, m16);
            float alpha = exp2f(mrq - mnew);
            mrq = mnew;
            lrq *= alpha;
            float alr[4];
            #pragma unroll
            for (int r = 0; r < 4; r++) alr[r] = __shfl(alpha, l4*4 + r);
            #pragma unroll
            for (int nd = 0; nd < 4; nd++)
                #pragma unroll
                for (int r = 0; r < 4; r++) o[nd][r] *= alr[r];
        }

        float rs = 0.f;
        #pragma unroll
        for (int ni = 0; ni < 4; ni++)
            #pragma unroll
            for (int r = 0; r < 4; r++) {
                float p = exp2f(st[ni][r] - mrq);
                st[ni][r] = p;
                rs += p;
            }
        rs += __shfl_xor(rs, 16);
        rs += __shfl_xor(rs, 32);
        lrq += rs;

        // P -> LDS (swizzled)
        #pragma unroll
        for (int ni = 0; ni < 4; ni++) {
            half4v pk;
            #pragma unroll
            for (int r = 0; r < 4; r++) pk[r] = (f16)st[ni][r];
            int byte = (l15 * 128 + (ni*16 + l4*4) * 2) ^ ((l15 & 7) << 4);
            *(half4v*)(sP + byte) = pk;
        }

        // PV: A = P rows (q=l15), B = V^T frags from LDS
        #pragma unroll
        for (int kk = 0; kk < 2; kk++) {
            int pbyte = (l15 * 128 + (kk*32 + l4*8) * 2) ^ ((l15 & 7) << 4);
            half8 pa = *(const half8*)(sP + pbyte);
            #pragma unroll
            for (int nd = 0; nd < 4; nd++) {
                int row = nd * 16 + l15;
                half8 bv = *(const half8*)(Vb + row * 128 + ((kk*64 + l4*16) ^ ((row & 7) << 4)));
                o[nd] = MFMA16(pa, bv, o[nd]);
            }
        }

        __syncthreads();   // drains vmcnt (staged tile ready) + guards buffer reuse
    }
    #undef STAGE

    // epilogue
    float lrr[4];
    #pragma unroll
    for (int r = 0; r < 4; r++) lrr[r] = 1.f / __shfl(lrq, l4*4 + r);

    f16* Op = obuf + (size_t)b * 1024 * 768 + h * 64;
    #pragma unroll
    for (int nd = 0; nd < 4; nd++)
        #pragma unroll
        for (int r = 0; r < 4; r++) {
            int qi = q0 + l4 * 4 + r;
            int d  = nd * 16 + l15;
            Op[(size_t)qi * 768 + d] = (f16)(o[nd][r] * lrr[r]);
        }
}

extern "C" void kernel_launch(void* const* d_in, const int* in_sizes, int n_in,
                              void* d_out, int out_size, void* d_ws, size_t ws_size,
                              hipStream_t stream) {
    const float* x      = (const float*)d_in[0];
    const float* w_qkv  = (const float*)d_in[1];
    const float* w_proj = (const float*)d_in[2];
    const float* b_proj = (const float*)d_in[3];
    float* out = (float*)d_out;
    char* ws = (char*)d_ws;

    // workspace layout (bytes)
    f16* x_h      = (f16*)(ws + 0);          // 8192x768      12,582,912
    f16* w_qkv_t  = (f16*)(ws + 12582912);   // 2304x768       3,538,944
    f16* w_proj_t = (f16*)(ws + 16121856);   // 768x768        1,179,648
    f16* qb       = (f16*)(ws + 17301504);   // 96x1024x64    12,582,912
    f16* kb       = (f16*)(ws + 29884416);   // 96x1024x64    12,582,912
    f16* vtb      = (f16*)(ws + 42467328);   // 96x64x1024    12,582,912
    f16* ob       = (f16*)(ws + 55050240);   // 8192x768      12,582,912

    cast_f32_to_f16<<<dim3(6144), dim3(256), 0, stream>>>(x, x_h, 6291456 / 4);
    transpose_cast<<<dim3(2304 / 32, 768 / 32), dim3(256), 0, stream>>>(w_qkv, w_qkv_t, 768, 2304);
    transpose_cast<<<dim3(768 / 32, 768 / 32), dim3(256), 0, stream>>>(w_proj, w_proj_t, 768, 768);
    gemm_bt<0><<<dim3(2304 / 128, 8192 / 128), dim3(256), 0, stream>>>(
        x_h, w_qkv_t, qb, kb, vtb, nullptr, nullptr);
    attn_kernel<<<dim3(1024 / 64, 96), dim3(256), 0, stream>>>(qb, kb, vtb, ob);
    gemm_bt<1><<<dim3(768 / 128, 8192 / 128), dim3(256), 0, stream>>>(
        ob, w_proj_t, nullptr, nullptr, nullptr, out, b_proj);
}

// Round 5
// 162.115 us; speedup vs baseline: 1.9208x; 1.0261x over previous
//
#include <hip/hip_runtime.h>

typedef _Float16 f16;
typedef _Float16 half8 __attribute__((ext_vector_type(8)));
typedef _Float16 half4v __attribute__((ext_vector_type(4)));
typedef float f32x4 __attribute__((ext_vector_type(4)));

#define MFMA16(a,b,c) __builtin_amdgcn_mfma_f32_16x16x32_f16((a),(b),(c),0,0,0)

__device__ __forceinline__ void gload_lds16(const f16* g, f16* l) {
    __builtin_amdgcn_global_load_lds(
        (const __attribute__((address_space(1))) unsigned int*)g,
        (__attribute__((address_space(3))) unsigned int*)l, 16, 0, 0);
}

// ---------------- cast fp32 -> fp16 (vectorized) ----------------
__global__ void cast_f32_to_f16(const float* __restrict__ in, f16* __restrict__ out, int n4) {
    int i = blockIdx.x * blockDim.x + threadIdx.x;
    if (i < n4) {
        float4 v = ((const float4*)in)[i];
        half4v h;
        h.x = (f16)v.x; h.y = (f16)v.y; h.z = (f16)v.z; h.w = (f16)v.w;
        ((half4v*)out)[i] = h;
    }
}

// ---------------- transpose + cast: in[K][N] fp32 -> out[N][K] fp16 ----------------
__global__ void transpose_cast(const float* __restrict__ in, f16* __restrict__ out, int K, int N) {
    __shared__ f16 tile[32][33];
    int n0 = blockIdx.x * 32, k0 = blockIdx.y * 32;
    int tx = threadIdx.x & 31, ty = threadIdx.x >> 5;   // 256 threads = 32x8
    for (int r = ty; r < 32; r += 8)
        tile[r][tx] = (f16)in[(size_t)(k0 + r) * N + (n0 + tx)];
    __syncthreads();
    for (int r = ty; r < 32; r += 8)
        out[(size_t)(n0 + r) * K + (k0 + tx)] = tile[tx][r];
}

// ---------------- GEMM: C[M][N] = A[M][768] * Bt[N][768]^T ----------------
// 3-buffer depth-2 prefetch, counted vmcnt(4) (T4), raw s_barrier, XCD swizzle (T1).
// MODE 0: qkv scatter epilogue (NX=18). MODE 1: proj + bias (NX=6).
template<int MODE>
__global__ __launch_bounds__(256, 3)
void gemm_bt(const f16* __restrict__ A, const f16* __restrict__ Bt,
             f16* __restrict__ qbuf, f16* __restrict__ kbuf, f16* __restrict__ vtbuf,
             float* __restrict__ out, const float* __restrict__ bias)
{
    constexpr int K = 768;
    constexpr int NX = (MODE == 0) ? 18 : 6;   // n-tiles
    constexpr int NWG = NX * 64;
    __shared__ __align__(16) f16 As[3][128 * 32];
    __shared__ __align__(16) f16 Bs[3][128 * 32];
    const int tid  = threadIdx.x;
    const int lane = tid & 63, wave = tid >> 6;
    const int wm = wave >> 1, wn = wave & 1;          // 2x2 waves, 64x64 each
    const int l15 = lane & 15, l4 = lane >> 4;

    // XCD-aware bijective swizzle (NWG % 8 == 0): contiguous chunk per XCD
    const int bid = blockIdx.x;
    const int swz = (bid & 7) * (NWG / 8) + (bid >> 3);
    const int m0 = (swz / NX) * 128, n0 = (swz % NX) * 128;

    const int srow  = lane >> 2;          // 0..15 row within staging instr
    const int sslot = lane & 3;           // 16B slot within 64B row

    f32x4 acc[4][4] = {};

    // stage one 128x32 tile of A and B into buf (linear LDS, 4 gload/thread)
    #define GSTAGE(buf, kt) do {                                                     \
        _Pragma("unroll")                                                            \
        for (int i = 0; i < 2; ++i) {                                                \
            int rbase = i * 64 + wave * 16;                                          \
            int row = rbase + srow;                                                  \
            gload_lds16(A  + (size_t)(m0 + row) * K + (kt) + sslot * 8, &As[buf][rbase * 32]); \
            gload_lds16(Bt + (size_t)(n0 + row) * K + (kt) + sslot * 8, &Bs[buf][rbase * 32]); \
        }                                                                            \
    } while (0)

    GSTAGE(0, 0);
    GSTAGE(1, 32);

    int cur = 0;
    for (int t = 0; t < 24; ++t) {
        // wait: own stage(t) retired; stage(t+1) (newest 4) stays in flight across barrier
        if (t < 23) asm volatile("s_waitcnt vmcnt(4)" ::: "memory");
        else        asm volatile("s_waitcnt vmcnt(0)" ::: "memory");
        __builtin_amdgcn_s_barrier();
        // stage(t+2) into the buffer whose reads all completed before the barrier
        if (t < 22) {
            int nb = cur + 2; if (nb >= 3) nb -= 3;
            GSTAGE(nb, (t + 2) * 32);
        }
        half8 af[4], bf[4];
        #pragma unroll
        for (int mi = 0; mi < 4; mi++) af[mi] = *(const half8*)&As[cur][(wm*64 + mi*16 + l15) * 32 + l4*8];
        #pragma unroll
        for (int ni = 0; ni < 4; ni++) bf[ni] = *(const half8*)&Bs[cur][(wn*64 + ni*16 + l15) * 32 + l4*8];
        #pragma unroll
        for (int mi = 0; mi < 4; mi++)
            #pragma unroll
            for (int ni = 0; ni < 4; ni++)
                acc[mi][ni] = MFMA16(af[mi], bf[ni], acc[mi][ni]);
        if (++cur >= 3) cur = 0;
    }
    #undef GSTAGE

    #pragma unroll
    for (int mi = 0; mi < 4; mi++) {
        #pragma unroll
        for (int ni = 0; ni < 4; ni++) {
            #pragma unroll
            for (int r = 0; r < 4; r++) {
                int gm = m0 + wm*64 + mi*16 + l4*4 + r;   // C row
                int gn = n0 + wn*64 + ni*16 + l15;        // C col
                float v = acc[mi][ni][r];
                if (MODE == 0) {
                    int t = gn / 768, rem = gn % 768;
                    int hh = rem >> 6, dd = rem & 63;
                    int bb = gm >> 10, ii = gm & 1023;
                    int bhh = bb * 12 + hh;
                    f16 hv = (f16)v;
                    if (t == 0)      qbuf[((size_t)bhh * 1024 + ii) * 64 + dd] = hv;
                    else if (t == 1) kbuf[((size_t)bhh * 1024 + ii) * 64 + dd] = hv;
                    else             vtbuf[((size_t)bhh * 64 + dd) * 1024 + ii] = hv;
                } else {
                    out[(size_t)gm * 768 + gn] = v + bias[gn];
                }
            }
        }
    }
}

// ---------------- flash attention: LDS-staged K/V (double-buffered), swapped-QK ----------------
// Block = one head, 64 queries; 4 waves x 16 queries. KV tile = 64.
__global__ __launch_bounds__(256, 4)
void attn_kernel(const f16* __restrict__ qbuf, const f16* __restrict__ kbuf,
                 const f16* __restrict__ vtbuf, f16* __restrict__ obuf)
{
    __shared__ __align__(16) f16 Ks[2][4096];   // [buf][64 keys][64 d], XOR-swizzled content
    __shared__ __align__(16) f16 Vs[2][4096];   // [buf][64 d][64 keys], XOR-swizzled content
    __shared__ __align__(16) char sPall[4 * 2048];  // per-wave 16x64 f16 P tile
    const int tid = threadIdx.x;
    const int lane = tid & 63, wave = tid >> 6;
    char* sP = sPall + wave * 2048;
    const int bh = blockIdx.y;              // 0..95
    const int b = bh / 12, h = bh % 12;
    const int q0 = blockIdx.x * 64 + wave * 16;
    const int l15 = lane & 15, l4 = lane >> 4;

    const f16* Q  = qbuf  + (size_t)bh * 65536;
    const f16* Kp = kbuf  + (size_t)bh * 65536;
    const f16* Vt = vtbuf + (size_t)bh * 65536;

    // Q fragment (B-operand of swapped QK), pre-scaled by scale*log2(e)
    const f16 slh = (f16)(0.125f * 1.44269504089f);
    half8 aq[2];
    aq[0] = *(const half8*)&Q[(q0 + l15) * 64 + l4 * 8];
    aq[1] = *(const half8*)&Q[(q0 + l15) * 64 + 32 + l4 * 8];
    #pragma unroll
    for (int j = 0; j < 8; j++) { aq[0][j] *= slh; aq[1][j] *= slh; }

    // staging geometry (pre-swizzled source, linear LDS dest)
    const int srow8 = lane >> 3;            // 0..7 (row within 8-row group = row&7)
    const int c16   = (lane & 7) ^ srow8;   // inverse-swizzled source slot

    f32x4 o[4] = {};
    float mrq = -1e30f, lrq = 0.f;

    #define STAGE(buf, kv) do {                                                     \
        _Pragma("unroll")                                                           \
        for (int i = 0; i < 2; ++i) {                                               \
            int rbase = wave * 16 + i * 8;                                          \
            int rl = rbase + srow8;                                                 \
            gload_lds16(Kp + (size_t)((kv) + rl) * 64 + c16 * 8, &Ks[buf][rbase * 64]); \
            gload_lds16(Vt + (size_t)rl * 1024 + (kv) + c16 * 8, &Vs[buf][rbase * 64]); \
        }                                                                           \
    } while (0)

    STAGE(0, 0);
    __syncthreads();

    for (int t = 0; t < 16; ++t) {
        const int cur = t & 1;
        if (t < 15) STAGE(cur ^ 1, (t + 1) * 64);   // in flight during compute

        const char* Kb = (const char*)&Ks[cur][0];
        const char* Vb = (const char*)&Vs[cur][0];

        // swapped QK: St[key][query] (log2 domain, scale pre-folded into aq)
        f32x4 st[4];
        #pragma unroll
        for (int ni = 0; ni < 4; ni++) {
            int row = ni * 16 + l15;
            int sw = ((row & 7) << 4);
            half8 k0 = *(const half8*)(Kb + row * 128 + ((l4 * 16) ^ sw));
            half8 k1 = *(const half8*)(Kb + row * 128 + ((64 + l4 * 16) ^ sw));
            f32x4 z = {0.f, 0.f, 0.f, 0.f};
            z = MFMA16(k0, aq[0], z);
            st[ni] = MFMA16(k1, aq[1], z);
        }

        // row max (lane holds 16 keys for query l15)
        float m16 = st[0][0];
        #pragma unroll
        for (int ni = 0; ni < 4; ni++)
            #pragma unroll
            for (int r = 0; r < 4; r++) m16 = fmaxf(m16, st[ni][r]);
        m16 = fmaxf(m16, __shfl_xor(m16, 16));
        m16 = fmaxf(m16, __shfl_xor(m16, 32));

        // defer-max (T13): rescale only when max grew by > 11 (log2) for any query
        if (!__all(m16 - mrq <= 11.0f)) {
            float mnew = fmaxf(mrq, m16);
            float alpha = exp2f(mrq - mnew);
            mrq = mnew;
            lrq *= alpha;
            float alr[4];
            #pragma unroll
            for (int r = 0; r < 4; r++) alr[r] = __shfl(alpha, l4*4 + r);
            #pragma unroll
            for (int nd = 0; nd < 4; nd++)
                #pragma unroll
                for (int r = 0; r < 4; r++) o[nd][r] *= alr[r];
        }

        float rs = 0.f;
        #pragma unroll
        for (int ni = 0; ni < 4; ni++)
            #pragma unroll
            for (int r = 0; r < 4; r++) {
                float p = exp2f(st[ni][r] - mrq);
                st[ni][r] = p;
                rs += p;
            }
        rs += __shfl_xor(rs, 16);
        rs += __shfl_xor(rs, 32);
        lrq += rs;

        // P -> LDS (swizzled)
        #pragma unroll
        for (int ni = 0; ni < 4; ni++) {
            half4v pk;
            #pragma unroll
            for (int r = 0; r < 4; r++) pk[r] = (f16)st[ni][r];
            int byte = (l15 * 128 + (ni*16 + l4*4) * 2) ^ ((l15 & 7) << 4);
            *(half4v*)(sP + byte) = pk;
        }

        // PV: A = P rows (q=l15), B = V^T frags from LDS
        #pragma unroll
        for (int kk = 0; kk < 2; kk++) {
            int pbyte = (l15 * 128 + (kk*32 + l4*8) * 2) ^ ((l15 & 7) << 4);
            half8 pa = *(const half8*)(sP + pbyte);
            #pragma unroll
            for (int nd = 0; nd < 4; nd++) {
                int row = nd * 16 + l15;
                half8 bv = *(const half8*)(Vb + row * 128 + ((kk*64 + l4*16) ^ ((row & 7) << 4)));
                o[nd] = MFMA16(pa, bv, o[nd]);
            }
        }

        __syncthreads();   // drains vmcnt (staged tile ready) + guards buffer reuse
    }
    #undef STAGE

    // epilogue
    float lrr[4];
    #pragma unroll
    for (int r = 0; r < 4; r++) lrr[r] = 1.f / __shfl(lrq, l4*4 + r);

    f16* Op = obuf + (size_t)b * 1024 * 768 + h * 64;
    #pragma unroll
    for (int nd = 0; nd < 4; nd++)
        #pragma unroll
        for (int r = 0; r < 4; r++) {
            int qi = q0 + l4 * 4 + r;
            int d  = nd * 16 + l15;
            Op[(size_t)qi * 768 + d] = (f16)(o[nd][r] * lrr[r]);
        }
}

extern "C" void kernel_launch(void* const* d_in, const int* in_sizes, int n_in,
                              void* d_out, int out_size, void* d_ws, size_t ws_size,
                              hipStream_t stream) {
    const float* x      = (const float*)d_in[0];
    const float* w_qkv  = (const float*)d_in[1];
    const float* w_proj = (const float*)d_in[2];
    const float* b_proj = (const float*)d_in[3];
    float* out = (float*)d_out;
    char* ws = (char*)d_ws;

    // workspace layout (bytes)
    f16* x_h      = (f16*)(ws + 0);          // 8192x768      12,582,912
    f16* w_qkv_t  = (f16*)(ws + 12582912);   // 2304x768       3,538,944
    f16* w_proj_t = (f16*)(ws + 16121856);   // 768x768        1,179,648
    f16* qb       = (f16*)(ws + 17301504);   // 96x1024x64    12,582,912
    f16* kb       = (f16*)(ws + 29884416);   // 96x1024x64    12,582,912
    f16* vtb      = (f16*)(ws + 42467328);   // 96x64x1024    12,582,912
    f16* ob       = (f16*)(ws + 55050240);   // 8192x768      12,582,912

    cast_f32_to_f16<<<dim3(6144), dim3(256), 0, stream>>>(x, x_h, 6291456 / 4);
    transpose_cast<<<dim3(2304 / 32, 768 / 32), dim3(256), 0, stream>>>(w_qkv, w_qkv_t, 768, 2304);
    transpose_cast<<<dim3(768 / 32, 768 / 32), dim3(256), 0, stream>>>(w_proj, w_proj_t, 768, 768);
    gemm_bt<0><<<dim3(18 * 64), dim3(256), 0, stream>>>(
        x_h, w_qkv_t, qb, kb, vtb, nullptr, nullptr);
    attn_kernel<<<dim3(1024 / 64, 96), dim3(256), 0, stream>>>(qb, kb, vtb, ob);
    gemm_bt<1><<<dim3(6 * 64), dim3(256), 0, stream>>>(
        ob, w_proj_t, nullptr, nullptr, nullptr, out, b_proj);
}

// Round 6
// 137.697 us; speedup vs baseline: 2.2614x; 1.1773x over previous
//
#include <hip/hip_runtime.h>

typedef _Float16 f16;
typedef _Float16 half8 __attribute__((ext_vector_type(8)));
typedef _Float16 half4v __attribute__((ext_vector_type(4)));
typedef float f32x4 __attribute__((ext_vector_type(4)));

#define MFMA16(a,b,c) __builtin_amdgcn_mfma_f32_16x16x32_f16((a),(b),(c),0,0,0)

__device__ __forceinline__ void gload_lds16(const f16* g, f16* l) {
    __builtin_amdgcn_global_load_lds(
        (const __attribute__((address_space(1))) unsigned int*)g,
        (__attribute__((address_space(3))) unsigned int*)l, 16, 0, 0);
}

// ---------------- cast fp32 -> fp16 (vectorized) ----------------
__global__ void cast_f32_to_f16(const float* __restrict__ in, f16* __restrict__ out, int n4) {
    int i = blockIdx.x * blockDim.x + threadIdx.x;
    if (i < n4) {
        float4 v = ((const float4*)in)[i];
        half4v h;
        h.x = (f16)v.x; h.y = (f16)v.y; h.z = (f16)v.z; h.w = (f16)v.w;
        ((half4v*)out)[i] = h;
    }
}

// ---------------- transpose + cast: in[K][N] fp32 -> out[N][K] fp16 ----------------
__global__ void transpose_cast(const float* __restrict__ in, f16* __restrict__ out, int K, int N) {
    __shared__ f16 tile[32][33];
    int n0 = blockIdx.x * 32, k0 = blockIdx.y * 32;
    int tx = threadIdx.x & 31, ty = threadIdx.x >> 5;   // 256 threads = 32x8
    for (int r = ty; r < 32; r += 8)
        tile[r][tx] = (f16)in[(size_t)(k0 + r) * N + (n0 + tx)];
    __syncthreads();
    for (int r = ty; r < 32; r += 8)
        out[(size_t)(n0 + r) * K + (k0 + tx)] = tile[tx][r];
}

// ---------------- GEMM: C[M][N] = A[M][768] * Bt[N][768]^T ----------------
// 3-buffer depth-2 prefetch, counted vmcnt(4), raw s_barrier, XCD swizzle.
// MODE 0: qkv epilogue via LDS roundtrip -> coalesced stores. MODE 1: proj + bias.
template<int MODE>
__global__ __launch_bounds__(256, 3)
void gemm_bt(const f16* __restrict__ A, const f16* __restrict__ Bt,
             f16* __restrict__ qbuf, f16* __restrict__ kbuf, f16* __restrict__ vtbuf,
             float* __restrict__ out, const float* __restrict__ bias)
{
    constexpr int K = 768;
    constexpr int NX = (MODE == 0) ? 18 : 6;   // n-tiles
    constexpr int NWG = NX * 64;
    __shared__ __align__(16) char smem[49152];
    f16* As = (f16*)smem;              // [3][128*32]
    f16* Bs = (f16*)(smem + 24576);    // [3][128*32]
    const int tid  = threadIdx.x;
    const int lane = tid & 63, wave = tid >> 6;
    const int wm = wave >> 1, wn = wave & 1;          // 2x2 waves, 64x64 each
    const int l15 = lane & 15, l4 = lane >> 4;

    // XCD-aware bijective swizzle (NWG % 8 == 0)
    const int bid = blockIdx.x;
    const int swz = (bid & 7) * (NWG / 8) + (bid >> 3);
    const int m0 = (swz / NX) * 128, n0 = (swz % NX) * 128;

    const int srow  = lane >> 2;          // 0..15 row within staging instr
    const int sslot = lane & 3;           // 16B slot within 64B row

    f32x4 acc[4][4] = {};

    #define GSTAGE(buf, kt) do {                                                     \
        _Pragma("unroll")                                                            \
        for (int i = 0; i < 2; ++i) {                                                \
            int rbase = i * 64 + wave * 16;                                          \
            int row = rbase + srow;                                                  \
            gload_lds16(A  + (size_t)(m0 + row) * K + (kt) + sslot * 8, &As[(buf) * 4096 + rbase * 32]); \
            gload_lds16(Bt + (size_t)(n0 + row) * K + (kt) + sslot * 8, &Bs[(buf) * 4096 + rbase * 32]); \
        }                                                                            \
    } while (0)

    GSTAGE(0, 0);
    GSTAGE(1, 32);

    int cur = 0;
    for (int t = 0; t < 24; ++t) {
        if (t < 23) asm volatile("s_waitcnt vmcnt(4)" ::: "memory");
        else        asm volatile("s_waitcnt vmcnt(0)" ::: "memory");
        __builtin_amdgcn_s_barrier();
        if (t < 22) {
            int nb = cur + 2; if (nb >= 3) nb -= 3;
            GSTAGE(nb, (t + 2) * 32);
        }
        half8 af[4], bf[4];
        #pragma unroll
        for (int mi = 0; mi < 4; mi++) af[mi] = *(const half8*)&As[cur*4096 + (wm*64 + mi*16 + l15) * 32 + l4*8];
        #pragma unroll
        for (int ni = 0; ni < 4; ni++) bf[ni] = *(const half8*)&Bs[cur*4096 + (wn*64 + ni*16 + l15) * 32 + l4*8];
        #pragma unroll
        for (int mi = 0; mi < 4; mi++)
            #pragma unroll
            for (int ni = 0; ni < 4; ni++)
                acc[mi][ni] = MFMA16(af[mi], bf[ni], acc[mi][ni]);
        if (++cur >= 3) cur = 0;
    }
    #undef GSTAGE

    if (MODE == 0) {
        // ---- LDS-roundtrip epilogue: coalesced stores ----
        __syncthreads();
        f16* sC = (f16*)smem;          // [128][136] (stride 136 halfs = 272B, 16B-aligned rows)
        const int t3 = n0 / 768;                 // which of q/k/v
        const int bb = m0 >> 10;                 // batch
        const int mo = m0 & 1023;                // row offset in batch
        const int h0 = (n0 - t3 * 768) >> 6;     // first head in tile (2 heads per 128 cols)

        if (t3 < 2) {
            // row-major: sC[row][col]
            #pragma unroll
            for (int mi = 0; mi < 4; mi++)
                #pragma unroll
                for (int ni = 0; ni < 4; ni++)
                    #pragma unroll
                    for (int r = 0; r < 4; r++) {
                        int row = wm*64 + mi*16 + l4*4 + r;
                        int col = wn*64 + ni*16 + l15;
                        sC[row * 136 + col] = (f16)acc[mi][ni][r];
                    }
            __syncthreads();
            f16* outb = (t3 == 0) ? qbuf : kbuf;
            #pragma unroll
            for (int hc = 0; hc < 2; hc++) {
                f16* base = outb + ((size_t)(bb * 12 + h0 + hc) * 1024 + mo) * 64;
                #pragma unroll
                for (int i = 0; i < 4; i++) {
                    int row = wave * 32 + i * 8 + (lane >> 3);
                    int cc  = (lane & 7) * 8;
                    half8 v = *(const half8*)&sC[row * 136 + hc * 64 + cc];
                    *(half8*)(base + row * 64 + cc) = v;   // 1KB contiguous per wave-instr
                }
            }
        } else {
            // transposed: sC[col][row] (half4 packed along row)
            #pragma unroll
            for (int mi = 0; mi < 4; mi++)
                #pragma unroll
                for (int ni = 0; ni < 4; ni++) {
                    int row0 = wm*64 + mi*16 + l4*4;
                    int col  = wn*64 + ni*16 + l15;
                    half4v pk;
                    #pragma unroll
                    for (int r = 0; r < 4; r++) pk[r] = (f16)acc[mi][ni][r];
                    *(half4v*)&sC[col * 136 + row0] = pk;
                }
            __syncthreads();
            #pragma unroll
            for (int i = 0; i < 8; i++) {
                int col = wave * 32 + i * 4 + (lane >> 4);
                int rc  = (lane & 15) * 8;
                half8 v = *(const half8*)&sC[col * 136 + rc];
                int head = h0 + (col >> 6), dd = col & 63;
                *(half8*)(vtbuf + ((size_t)(bb * 12 + head) * 64 + dd) * 1024 + mo + rc) = v;
            }
        }
    } else {
        #pragma unroll
        for (int mi = 0; mi < 4; mi++)
            #pragma unroll
            for (int ni = 0; ni < 4; ni++)
                #pragma unroll
                for (int r = 0; r < 4; r++) {
                    int gm = m0 + wm*64 + mi*16 + l4*4 + r;
                    int gn = n0 + wn*64 + ni*16 + l15;
                    out[(size_t)gm * 768 + gn] = acc[mi][ni][r] + bias[gn];
                }
    }
}

// ---------------- flash attention: LDS-staged K/V (double-buffered), swapped-QK ----------------
__global__ __launch_bounds__(256, 4)
void attn_kernel(const f16* __restrict__ qbuf, const f16* __restrict__ kbuf,
                 const f16* __restrict__ vtbuf, f16* __restrict__ obuf)
{
    __shared__ __align__(16) f16 Ks[2][4096];
    __shared__ __align__(16) f16 Vs[2][4096];
    __shared__ __align__(16) char sPall[4 * 2048];
    const int tid = threadIdx.x;
    const int lane = tid & 63, wave = tid >> 6;
    char* sP = sPall + wave * 2048;
    const int bh = blockIdx.y;
    const int b = bh / 12, h = bh % 12;
    const int q0 = blockIdx.x * 64 + wave * 16;
    const int l15 = lane & 15, l4 = lane >> 4;

    const f16* Q  = qbuf  + (size_t)bh * 65536;
    const f16* Kp = kbuf  + (size_t)bh * 65536;
    const f16* Vt = vtbuf + (size_t)bh * 65536;

    const f16 slh = (f16)(0.125f * 1.44269504089f);
    half8 aq[2];
    aq[0] = *(const half8*)&Q[(q0 + l15) * 64 + l4 * 8];
    aq[1] = *(const half8*)&Q[(q0 + l15) * 64 + 32 + l4 * 8];
    #pragma unroll
    for (int j = 0; j < 8; j++) { aq[0][j] *= slh; aq[1][j] *= slh; }

    const int srow8 = lane >> 3;
    const int c16   = (lane & 7) ^ srow8;

    f32x4 o[4] = {};
    float mrq = -1e30f, lrq = 0.f;

    #define STAGE(buf, kv) do {                                                     \
        _Pragma("unroll")                                                           \
        for (int i = 0; i < 2; ++i) {                                               \
            int rbase = wave * 16 + i * 8;                                          \
            int rl = rbase + srow8;                                                 \
            gload_lds16(Kp + (size_t)((kv) + rl) * 64 + c16 * 8, &Ks[buf][rbase * 64]); \
            gload_lds16(Vt + (size_t)rl * 1024 + (kv) + c16 * 8, &Vs[buf][rbase * 64]); \
        }                                                                           \
    } while (0)

    STAGE(0, 0);
    __syncthreads();

    for (int t = 0; t < 16; ++t) {
        const int cur = t & 1;
        if (t < 15) STAGE(cur ^ 1, (t + 1) * 64);

        const char* Kb = (const char*)&Ks[cur][0];
        const char* Vb = (const char*)&Vs[cur][0];

        f32x4 st[4];
        #pragma unroll
        for (int ni = 0; ni < 4; ni++) {
            int row = ni * 16 + l15;
            int sw = ((row & 7) << 4);
            half8 k0 = *(const half8*)(Kb + row * 128 + ((l4 * 16) ^ sw));
            half8 k1 = *(const half8*)(Kb + row * 128 + ((64 + l4 * 16) ^ sw));
            f32x4 z = {0.f, 0.f, 0.f, 0.f};
            z = MFMA16(k0, aq[0], z);
            st[ni] = MFMA16(k1, aq[1], z);
        }

        float m16 = st[0][0];
        #pragma unroll
        for (int ni = 0; ni < 4; ni++)
            #pragma unroll
            for (int r = 0; r < 4; r++) m16 = fmaxf(m16, st[ni][r]);
        m16 = fmaxf(m16, __shfl_xor(m16, 16));
        m16 = fmaxf(m16, __shfl_xor(m16, 32));

        if (!__all(m16 - mrq <= 11.0f)) {
            float mnew = fmaxf(mrq, m16);
            float alpha = exp2f(mrq - mnew);
            mrq = mnew;
            lrq *= alpha;
            float alr[4];
            #pragma unroll
            for (int r = 0; r < 4; r++) alr[r] = __shfl(alpha, l4*4 + r);
            #pragma unroll
            for (int nd = 0; nd < 4; nd++)
                #pragma unroll
                for (int r = 0; r < 4; r++) o[nd][r] *= alr[r];
        }

        float rs = 0.f;
        #pragma unroll
        for (int ni = 0; ni < 4; ni++)
            #pragma unroll
            for (int r = 0; r < 4; r++) {
                float p = exp2f(st[ni][r] - mrq);
                st[ni][r] = p;
                rs += p;
            }
        rs += __shfl_xor(rs, 16);
        rs += __shfl_xor(rs, 32);
        lrq += rs;

        #pragma unroll
        for (int ni = 0; ni < 4; ni++) {
            half4v pk;
            #pragma unroll
            for (int r = 0; r < 4; r++) pk[r] = (f16)st[ni][r];
            int byte = (l15 * 128 + (ni*16 + l4*4) * 2) ^ ((l15 & 7) << 4);
            *(half4v*)(sP + byte) = pk;
        }

        #pragma unroll
        for (int kk = 0; kk < 2; kk++) {
            int pbyte = (l15 * 128 + (kk*32 + l4*8) * 2) ^ ((l15 & 7) << 4);
            half8 pa = *(const half8*)(sP + pbyte);
            #pragma unroll
            for (int nd = 0; nd < 4; nd++) {
                int row = nd * 16 + l15;
                half8 bv = *(const half8*)(Vb + row * 128 + ((kk*64 + l4*16) ^ ((row & 7) << 4)));
                o[nd] = MFMA16(pa, bv, o[nd]);
            }
        }

        __syncthreads();
    }
    #undef STAGE

    float lrr[4];
    #pragma unroll
    for (int r = 0; r < 4; r++) lrr[r] = 1.f / __shfl(lrq, l4*4 + r);

    f16* Op = obuf + (size_t)b * 1024 * 768 + h * 64;
    #pragma unroll
    for (int nd = 0; nd < 4; nd++)
        #pragma unroll
        for (int r = 0; r < 4; r++) {
            int qi = q0 + l4 * 4 + r;
            int d  = nd * 16 + l15;
            Op[(size_t)qi * 768 + d] = (f16)(o[nd][r] * lrr[r]);
        }
}

extern "C" void kernel_launch(void* const* d_in, const int* in_sizes, int n_in,
                              void* d_out, int out_size, void* d_ws, size_t ws_size,
                              hipStream_t stream) {
    const float* x      = (const float*)d_in[0];
    const float* w_qkv  = (const float*)d_in[1];
    const float* w_proj = (const float*)d_in[2];
    const float* b_proj = (const float*)d_in[3];
    float* out = (float*)d_out;
    char* ws = (char*)d_ws;

    f16* x_h      = (f16*)(ws + 0);
    f16* w_qkv_t  = (f16*)(ws + 12582912);
    f16* w_proj_t = (f16*)(ws + 16121856);
    f16* qb       = (f16*)(ws + 17301504);
    f16* kb       = (f16*)(ws + 29884416);
    f16* vtb      = (f16*)(ws + 42467328);
    f16* ob       = (f16*)(ws + 55050240);

    cast_f32_to_f16<<<dim3(6144), dim3(256), 0, stream>>>(x, x_h, 6291456 / 4);
    transpose_cast<<<dim3(2304 / 32, 768 / 32), dim3(256), 0, stream>>>(w_qkv, w_qkv_t, 768, 2304);
    transpose_cast<<<dim3(768 / 32, 768 / 32), dim3(256), 0, stream>>>(w_proj, w_proj_t, 768, 768);
    gemm_bt<0><<<dim3(18 * 64), dim3(256), 0, stream>>>(
        x_h, w_qkv_t, qb, kb, vtb, nullptr, nullptr);
    attn_kernel<<<dim3(1024 / 64, 96), dim3(256), 0, stream>>>(qb, kb, vtb, ob);
    gemm_bt<1><<<dim3(6 * 64), dim3(256), 0, stream>>>(
        ob, w_proj_t, nullptr, nullptr, nullptr, out, b_proj);
}

// Round 8
// 135.815 us; speedup vs baseline: 2.2928x; 1.0139x over previous
//
#include <hip/hip_runtime.h>

typedef _Float16 f16;
typedef _Float16 half8 __attribute__((ext_vector_type(8)));
typedef _Float16 half4v __attribute__((ext_vector_type(4)));
typedef __fp16 fp16x2 __attribute__((ext_vector_type(2)));
typedef float f32x4 __attribute__((ext_vector_type(4)));

#define MFMA16(a,b,c) __builtin_amdgcn_mfma_f32_16x16x32_f16((a),(b),(c),0,0,0)

__device__ __forceinline__ void gload_lds16(const f16* g, f16* l) {
    __builtin_amdgcn_global_load_lds(
        (const __attribute__((address_space(1))) unsigned int*)g,
        (__attribute__((address_space(3))) unsigned int*)l, 16, 0, 0);
}

// ---------------- cast fp32 -> fp16 (vectorized) ----------------
__global__ void cast_f32_to_f16(const float* __restrict__ in, f16* __restrict__ out, int n4) {
    int i = blockIdx.x * blockDim.x + threadIdx.x;
    if (i < n4) {
        float4 v = ((const float4*)in)[i];
        half4v h;
        h.x = (f16)v.x; h.y = (f16)v.y; h.z = (f16)v.z; h.w = (f16)v.w;
        ((half4v*)out)[i] = h;
    }
}

// ---------------- transpose + cast: in[K][N] fp32 -> out[N][K] fp16 ----------------
__global__ void transpose_cast(const float* __restrict__ in, f16* __restrict__ out, int K, int N) {
    __shared__ f16 tile[32][33];
    int n0 = blockIdx.x * 32, k0 = blockIdx.y * 32;
    int tx = threadIdx.x & 31, ty = threadIdx.x >> 5;   // 256 threads = 32x8
    for (int r = ty; r < 32; r += 8)
        tile[r][tx] = (f16)in[(size_t)(k0 + r) * N + (n0 + tx)];
    __syncthreads();
    for (int r = ty; r < 32; r += 8)
        out[(size_t)(n0 + r) * K + (k0 + tx)] = tile[tx][r];
}

// ---------------- GEMM: C[M][N] = A[M][768] * Bt[N][768]^T ----------------
// 3-buffer depth-2 prefetch, counted vmcnt(4), raw s_barrier, XCD swizzle.
// MODE 0: qkv epilogue via LDS roundtrip -> coalesced stores. MODE 1: proj + bias.
template<int MODE>
__global__ __launch_bounds__(256, 3)
void gemm_bt(const f16* __restrict__ A, const f16* __restrict__ Bt,
             f16* __restrict__ qbuf, f16* __restrict__ kbuf, f16* __restrict__ vtbuf,
             float* __restrict__ out, const float* __restrict__ bias)
{
    constexpr int K = 768;
    constexpr int NX = (MODE == 0) ? 18 : 6;   // n-tiles
    constexpr int NWG = NX * 64;
    __shared__ __align__(16) char smem[49152];
    f16* As = (f16*)smem;              // [3][128*32]
    f16* Bs = (f16*)(smem + 24576);    // [3][128*32]
    const int tid  = threadIdx.x;
    const int lane = tid & 63, wave = tid >> 6;
    const int wm = wave >> 1, wn = wave & 1;          // 2x2 waves, 64x64 each
    const int l15 = lane & 15, l4 = lane >> 4;

    // XCD-aware bijective swizzle (NWG % 8 == 0)
    const int bid = blockIdx.x;
    const int swz = (bid & 7) * (NWG / 8) + (bid >> 3);
    const int m0 = (swz / NX) * 128, n0 = (swz % NX) * 128;

    const int srow  = lane >> 2;          // 0..15 row within staging instr
    const int sslot = lane & 3;           // 16B slot within 64B row

    f32x4 acc[4][4] = {};

    #define GSTAGE(buf, kt) do {                                                     \
        _Pragma("unroll")                                                            \
        for (int i = 0; i < 2; ++i) {                                                \
            int rbase = i * 64 + wave * 16;                                          \
            int row = rbase + srow;                                                  \
            gload_lds16(A  + (size_t)(m0 + row) * K + (kt) + sslot * 8, &As[(buf) * 4096 + rbase * 32]); \
            gload_lds16(Bt + (size_t)(n0 + row) * K + (kt) + sslot * 8, &Bs[(buf) * 4096 + rbase * 32]); \
        }                                                                            \
    } while (0)

    GSTAGE(0, 0);
    GSTAGE(1, 32);

    int cur = 0;
    for (int t = 0; t < 24; ++t) {
        if (t < 23) asm volatile("s_waitcnt vmcnt(4)" ::: "memory");
        else        asm volatile("s_waitcnt vmcnt(0)" ::: "memory");
        __builtin_amdgcn_s_barrier();
        if (t < 22) {
            int nb = cur + 2; if (nb >= 3) nb -= 3;
            GSTAGE(nb, (t + 2) * 32);
        }
        half8 af[4], bf[4];
        #pragma unroll
        for (int mi = 0; mi < 4; mi++) af[mi] = *(const half8*)&As[cur*4096 + (wm*64 + mi*16 + l15) * 32 + l4*8];
        #pragma unroll
        for (int ni = 0; ni < 4; ni++) bf[ni] = *(const half8*)&Bs[cur*4096 + (wn*64 + ni*16 + l15) * 32 + l4*8];
        #pragma unroll
        for (int mi = 0; mi < 4; mi++)
            #pragma unroll
            for (int ni = 0; ni < 4; ni++)
                acc[mi][ni] = MFMA16(af[mi], bf[ni], acc[mi][ni]);
        if (++cur >= 3) cur = 0;
    }
    #undef GSTAGE

    if (MODE == 0) {
        // ---- LDS-roundtrip epilogue: coalesced stores ----
        __syncthreads();
        f16* sC = (f16*)smem;          // [128][136]
        const int t3 = n0 / 768;
        const int bb = m0 >> 10;
        const int mo = m0 & 1023;
        const int h0 = (n0 - t3 * 768) >> 6;

        if (t3 < 2) {
            #pragma unroll
            for (int mi = 0; mi < 4; mi++)
                #pragma unroll
                for (int ni = 0; ni < 4; ni++)
                    #pragma unroll
                    for (int r = 0; r < 4; r++) {
                        int row = wm*64 + mi*16 + l4*4 + r;
                        int col = wn*64 + ni*16 + l15;
                        sC[row * 136 + col] = (f16)acc[mi][ni][r];
                    }
            __syncthreads();
            f16* outb = (t3 == 0) ? qbuf : kbuf;
            #pragma unroll
            for (int hc = 0; hc < 2; hc++) {
                f16* base = outb + ((size_t)(bb * 12 + h0 + hc) * 1024 + mo) * 64;
                #pragma unroll
                for (int i = 0; i < 4; i++) {
                    int row = wave * 32 + i * 8 + (lane >> 3);
                    int cc  = (lane & 7) * 8;
                    half8 v = *(const half8*)&sC[row * 136 + hc * 64 + cc];
                    *(half8*)(base + row * 64 + cc) = v;
                }
            }
        } else {
            #pragma unroll
            for (int mi = 0; mi < 4; mi++)
                #pragma unroll
                for (int ni = 0; ni < 4; ni++) {
                    int row0 = wm*64 + mi*16 + l4*4;
                    int col  = wn*64 + ni*16 + l15;
                    half4v pk;
                    #pragma unroll
                    for (int r = 0; r < 4; r++) pk[r] = (f16)acc[mi][ni][r];
                    *(half4v*)&sC[col * 136 + row0] = pk;
                }
            __syncthreads();
            #pragma unroll
            for (int i = 0; i < 8; i++) {
                int col = wave * 32 + i * 4 + (lane >> 4);
                int rc  = (lane & 15) * 8;
                half8 v = *(const half8*)&sC[col * 136 + rc];
                int head = h0 + (col >> 6), dd = col & 63;
                *(half8*)(vtbuf + ((size_t)(bb * 12 + head) * 64 + dd) * 1024 + mo + rc) = v;
            }
        }
    } else {
        #pragma unroll
        for (int mi = 0; mi < 4; mi++)
            #pragma unroll
            for (int ni = 0; ni < 4; ni++)
                #pragma unroll
                for (int r = 0; r < 4; r++) {
                    int gm = m0 + wm*64 + mi*16 + l4*4 + r;
                    int gn = n0 + wn*64 + ni*16 + l15;
                    out[(size_t)gm * 768 + gn] = acc[mi][ni][r] + bias[gn];
                }
    }
}

// ---------------- flash attention: LDS-staged K/V (dbuf), swapped-QK ----------------
// VALU-lean softmax: max folded into MFMA acc-init, row-sum via ones-MFMA,
// packed cvt for P. Sync structure unchanged from R5.
__global__ __launch_bounds__(256, 4)
void attn_kernel(const f16* __restrict__ qbuf, const f16* __restrict__ kbuf,
                 const f16* __restrict__ vtbuf, f16* __restrict__ obuf)
{
    __shared__ __align__(16) f16 Ks[2][4096];
    __shared__ __align__(16) f16 Vs[2][4096];
    __shared__ __align__(16) char sPall[4 * 2048];
    const int tid = threadIdx.x;
    const int lane = tid & 63, wave = tid >> 6;
    char* sP = sPall + wave * 2048;
    const int bh = blockIdx.y;
    const int b = bh / 12, h = bh % 12;
    const int q0 = blockIdx.x * 64 + wave * 16;
    const int l15 = lane & 15, l4 = lane >> 4;

    const f16* Q  = qbuf  + (size_t)bh * 65536;
    const f16* Kp = kbuf  + (size_t)bh * 65536;
    const f16* Vt = vtbuf + (size_t)bh * 65536;

    const f16 slh = (f16)(0.125f * 1.44269504089f);
    half8 aq[2];
    aq[0] = *(const half8*)&Q[(q0 + l15) * 64 + l4 * 8];
    aq[1] = *(const half8*)&Q[(q0 + l15) * 64 + 32 + l4 * 8];
    #pragma unroll
    for (int j = 0; j < 8; j++) { aq[0][j] *= slh; aq[1][j] *= slh; }

    half8 ones;
    #pragma unroll
    for (int j = 0; j < 8; j++) ones[j] = (f16)1.0f;

    const int srow8 = lane >> 3;
    const int c16   = (lane & 7) ^ srow8;

    f32x4 o[4] = {};
    float lr4[4] = {0.f, 0.f, 0.f, 0.f};   // row-sum, row-owner layout (query l4*4+r)
    float mrq = 0.f;                        // running max for query l15 (log2 domain)

    #define STAGE(buf, kv) do {                                                     \
        _Pragma("unroll")                                                           \
        for (int i = 0; i < 2; ++i) {                                               \
            int rbase = wave * 16 + i * 8;                                          \
            int rl = rbase + srow8;                                                 \
            gload_lds16(Kp + (size_t)((kv) + rl) * 64 + c16 * 8, &Ks[buf][rbase * 64]); \
            gload_lds16(Vt + (size_t)rl * 1024 + (kv) + c16 * 8, &Vs[buf][rbase * 64]); \
        }                                                                           \
    } while (0)

    STAGE(0, 0);
    __syncthreads();

    for (int t = 0; t < 16; ++t) {
        const int cur = t & 1;
        if (t < 15) STAGE(cur ^ 1, (t + 1) * 64);

        const char* Kb = (const char*)&Ks[cur][0];
        const char* Vb = (const char*)&Vs[cur][0];

        // swapped QK with -mrq folded into acc init: st = S - mrq (log2 domain)
        f32x4 st[4];
        f32x4 zinit = {-mrq, -mrq, -mrq, -mrq};
        #pragma unroll
        for (int ni = 0; ni < 4; ni++) {
            int row = ni * 16 + l15;
            int sw = ((row & 7) << 4);
            half8 k0 = *(const half8*)(Kb + row * 128 + ((l4 * 16) ^ sw));
            half8 k1 = *(const half8*)(Kb + row * 128 + ((64 + l4 * 16) ^ sw));
            f32x4 z = MFMA16(k0, aq[0], zinit);
            st[ni] = MFMA16(k1, aq[1], z);
        }

        // relative row max (lane holds 16 keys for query l15)
        float m16 = fmaxf(fmaxf(st[0][0], st[0][1]), fmaxf(st[0][2], st[0][3]));
        #pragma unroll
        for (int ni = 1; ni < 4; ni++) {
            float a = fmaxf(fmaxf(st[ni][0], st[ni][1]), fmaxf(st[ni][2], st[ni][3]));
            m16 = fmaxf(m16, a);
        }
        m16 = fmaxf(m16, __shfl_xor(m16, 16));
        m16 = fmaxf(m16, __shfl_xor(m16, 32));

        // defer-max (T13): rescale only when relative max grew past THR=11
        if (!__all(m16 <= 11.0f)) {
            float d = fmaxf(m16, 0.f);
            float alpha = exp2f(-d);
            mrq += d;
            #pragma unroll
            for (int ni = 0; ni < 4; ni++)
                #pragma unroll
                for (int r = 0; r < 4; r++) st[ni][r] -= d;
            float alr[4];
            #pragma unroll
            for (int r = 0; r < 4; r++) alr[r] = __shfl(alpha, l4*4 + r);
            #pragma unroll
            for (int r = 0; r < 4; r++) lr4[r] *= alr[r];
            #pragma unroll
            for (int nd = 0; nd < 4; nd++)
                #pragma unroll
                for (int r = 0; r < 4; r++) o[nd][r] *= alr[r];
        }

        // P = exp2(st), packed-converted to f16, -> LDS (swizzled)
        #pragma unroll
        for (int ni = 0; ni < 4; ni++) {
            fp16x2 lo = __builtin_amdgcn_cvt_pkrtz(exp2f(st[ni][0]), exp2f(st[ni][1]));
            fp16x2 hi = __builtin_amdgcn_cvt_pkrtz(exp2f(st[ni][2]), exp2f(st[ni][3]));
            uint2 u;
            u.x = __builtin_bit_cast(unsigned int, lo);
            u.y = __builtin_bit_cast(unsigned int, hi);
            int byte = (l15 * 128 + (ni*16 + l4*4) * 2) ^ ((l15 & 7) << 4);
            *(uint2*)(sP + byte) = u;
        }

        // PV + row-sum via ones-MFMA (rs lands in row-owner layout)
        f32x4 racc = {0.f, 0.f, 0.f, 0.f};
        #pragma unroll
        for (int kk = 0; kk < 2; kk++) {
            int pbyte = (l15 * 128 + (kk*32 + l4*8) * 2) ^ ((l15 & 7) << 4);
            half8 pa = *(const half8*)(sP + pbyte);
            #pragma unroll
            for (int nd = 0; nd < 4; nd++) {
                int row = nd * 16 + l15;
                half8 bv = *(const half8*)(Vb + row * 128 + ((kk*64 + l4*16) ^ ((row & 7) << 4)));
                o[nd] = MFMA16(pa, bv, o[nd]);
            }
            racc = MFMA16(pa, ones, racc);
        }
        #pragma unroll
        for (int r = 0; r < 4; r++) lr4[r] += racc[r];

        __syncthreads();
    }
    #undef STAGE

    float lrr[4];
    #pragma unroll
    for (int r = 0; r < 4; r++) lrr[r] = 1.f / lr4[r];

    f16* Op = obuf + (size_t)b * 1024 * 768 + h * 64;
    #pragma unroll
    for (int nd = 0; nd < 4; nd++)
        #pragma unroll
        for (int r = 0; r < 4; r++) {
            int qi = q0 + l4 * 4 + r;
            int d  = nd * 16 + l15;
            Op[(size_t)qi * 768 + d] = (f16)(o[nd][r] * lrr[r]);
        }
}

extern "C" void kernel_launch(void* const* d_in, const int* in_sizes, int n_in,
                              void* d_out, int out_size, void* d_ws, size_t ws_size,
                              hipStream_t stream) {
    const float* x      = (const float*)d_in[0];
    const float* w_qkv  = (const float*)d_in[1];
    const float* w_proj = (const float*)d_in[2];
    const float* b_proj = (const float*)d_in[3];
    float* out = (float*)d_out;
    char* ws = (char*)d_ws;

    f16* x_h      = (f16*)(ws + 0);
    f16* w_qkv_t  = (f16*)(ws + 12582912);
    f16* w_proj_t = (f16*)(ws + 16121856);
    f16* qb       = (f16*)(ws + 17301504);
    f16* kb       = (f16*)(ws + 29884416);
    f16* vtb      = (f16*)(ws + 42467328);
    f16* ob       = (f16*)(ws + 55050240);

    cast_f32_to_f16<<<dim3(6144), dim3(256), 0, stream>>>(x, x_h, 6291456 / 4);
    transpose_cast<<<dim3(2304 / 32, 768 / 32), dim3(256), 0, stream>>>(w_qkv, w_qkv_t, 768, 2304);
    transpose_cast<<<dim3(768 / 32, 768 / 32), dim3(256), 0, stream>>>(w_proj, w_proj_t, 768, 768);
    gemm_bt<0><<<dim3(18 * 64), dim3(256), 0, stream>>>(
        x_h, w_qkv_t, qb, kb, vtb, nullptr, nullptr);
    attn_kernel<<<dim3(1024 / 64, 96), dim3(256), 0, stream>>>(qb, kb, vtb, ob);
    gemm_bt<1><<<dim3(6 * 64), dim3(256), 0, stream>>>(
        ob, w_proj_t, nullptr, nullptr, nullptr, out, b_proj);
}

// Round 9
// 127.571 us; speedup vs baseline: 2.4409x; 1.0646x over previous
//
#include <hip/hip_runtime.h>

typedef _Float16 f16;
typedef _Float16 half8 __attribute__((ext_vector_type(8)));
typedef _Float16 half4v __attribute__((ext_vector_type(4)));
typedef __fp16 fp16x2 __attribute__((ext_vector_type(2)));
typedef float f32x4 __attribute__((ext_vector_type(4)));
typedef float f32x16 __attribute__((ext_vector_type(16)));

#define MFMA16(a,b,c) __builtin_amdgcn_mfma_f32_16x16x32_f16((a),(b),(c),0,0,0)
#define MFMA32(a,b,c) __builtin_amdgcn_mfma_f32_32x32x16_f16((a),(b),(c),0,0,0)

__device__ __forceinline__ void gload_lds16(const f16* g, f16* l) {
    __builtin_amdgcn_global_load_lds(
        (const __attribute__((address_space(1))) unsigned int*)g,
        (__attribute__((address_space(3))) unsigned int*)l, 16, 0, 0);
}

// ---------------- cast fp32 -> fp16 (vectorized) ----------------
__global__ void cast_f32_to_f16(const float* __restrict__ in, f16* __restrict__ out, int n4) {
    int i = blockIdx.x * blockDim.x + threadIdx.x;
    if (i < n4) {
        float4 v = ((const float4*)in)[i];
        half4v h;
        h.x = (f16)v.x; h.y = (f16)v.y; h.z = (f16)v.z; h.w = (f16)v.w;
        ((half4v*)out)[i] = h;
    }
}

// ---------------- transpose + cast: in[K][N] fp32 -> out[N][K] fp16 ----------------
__global__ void transpose_cast(const float* __restrict__ in, f16* __restrict__ out, int K, int N) {
    __shared__ f16 tile[32][33];
    int n0 = blockIdx.x * 32, k0 = blockIdx.y * 32;
    int tx = threadIdx.x & 31, ty = threadIdx.x >> 5;   // 256 threads = 32x8
    for (int r = ty; r < 32; r += 8)
        tile[r][tx] = (f16)in[(size_t)(k0 + r) * N + (n0 + tx)];
    __syncthreads();
    for (int r = ty; r < 32; r += 8)
        out[(size_t)(n0 + r) * K + (k0 + tx)] = tile[tx][r];
}

// ---------------- GEMM: C[M][N] = A[M][768] * Bt[N][768]^T ----------------
// 3-buffer depth-2 prefetch, counted vmcnt(4), raw s_barrier, XCD swizzle.
// MODE 0: qkv epilogue via LDS roundtrip -> coalesced stores. MODE 1: proj + bias.
template<int MODE>
__global__ __launch_bounds__(256, 3)
void gemm_bt(const f16* __restrict__ A, const f16* __restrict__ Bt,
             f16* __restrict__ qbuf, f16* __restrict__ kbuf, f16* __restrict__ vtbuf,
             float* __restrict__ out, const float* __restrict__ bias)
{
    constexpr int K = 768;
    constexpr int NX = (MODE == 0) ? 18 : 6;   // n-tiles
    constexpr int NWG = NX * 64;
    __shared__ __align__(16) char smem[49152];
    f16* As = (f16*)smem;              // [3][128*32]
    f16* Bs = (f16*)(smem + 24576);    // [3][128*32]
    const int tid  = threadIdx.x;
    const int lane = tid & 63, wave = tid >> 6;
    const int wm = wave >> 1, wn = wave & 1;          // 2x2 waves, 64x64 each
    const int l15 = lane & 15, l4 = lane >> 4;

    // XCD-aware bijective swizzle (NWG % 8 == 0)
    const int bid = blockIdx.x;
    const int swz = (bid & 7) * (NWG / 8) + (bid >> 3);
    const int m0 = (swz / NX) * 128, n0 = (swz % NX) * 128;

    const int srow  = lane >> 2;          // 0..15 row within staging instr
    const int sslot = lane & 3;           // 16B slot within 64B row

    f32x4 acc[4][4] = {};

    #define GSTAGE(buf, kt) do {                                                     \
        _Pragma("unroll")                                                            \
        for (int i = 0; i < 2; ++i) {                                                \
            int rbase = i * 64 + wave * 16;                                          \
            int row = rbase + srow;                                                  \
            gload_lds16(A  + (size_t)(m0 + row) * K + (kt) + sslot * 8, &As[(buf) * 4096 + rbase * 32]); \
            gload_lds16(Bt + (size_t)(n0 + row) * K + (kt) + sslot * 8, &Bs[(buf) * 4096 + rbase * 32]); \
        }                                                                            \
    } while (0)

    GSTAGE(0, 0);
    GSTAGE(1, 32);

    int cur = 0;
    for (int t = 0; t < 24; ++t) {
        if (t < 23) asm volatile("s_waitcnt vmcnt(4)" ::: "memory");
        else        asm volatile("s_waitcnt vmcnt(0)" ::: "memory");
        __builtin_amdgcn_s_barrier();
        if (t < 22) {
            int nb = cur + 2; if (nb >= 3) nb -= 3;
            GSTAGE(nb, (t + 2) * 32);
        }
        half8 af[4], bf[4];
        #pragma unroll
        for (int mi = 0; mi < 4; mi++) af[mi] = *(const half8*)&As[cur*4096 + (wm*64 + mi*16 + l15) * 32 + l4*8];
        #pragma unroll
        for (int ni = 0; ni < 4; ni++) bf[ni] = *(const half8*)&Bs[cur*4096 + (wn*64 + ni*16 + l15) * 32 + l4*8];
        #pragma unroll
        for (int mi = 0; mi < 4; mi++)
            #pragma unroll
            for (int ni = 0; ni < 4; ni++)
                acc[mi][ni] = MFMA16(af[mi], bf[ni], acc[mi][ni]);
        if (++cur >= 3) cur = 0;
    }
    #undef GSTAGE

    if (MODE == 0) {
        // ---- LDS-roundtrip epilogue: coalesced stores ----
        __syncthreads();
        f16* sC = (f16*)smem;          // [128][136]
        const int t3 = n0 / 768;
        const int bb = m0 >> 10;
        const int mo = m0 & 1023;
        const int h0 = (n0 - t3 * 768) >> 6;

        if (t3 < 2) {
            #pragma unroll
            for (int mi = 0; mi < 4; mi++)
                #pragma unroll
                for (int ni = 0; ni < 4; ni++)
                    #pragma unroll
                    for (int r = 0; r < 4; r++) {
                        int row = wm*64 + mi*16 + l4*4 + r;
                        int col = wn*64 + ni*16 + l15;
                        sC[row * 136 + col] = (f16)acc[mi][ni][r];
                    }
            __syncthreads();
            f16* outb = (t3 == 0) ? qbuf : kbuf;
            #pragma unroll
            for (int hc = 0; hc < 2; hc++) {
                f16* base = outb + ((size_t)(bb * 12 + h0 + hc) * 1024 + mo) * 64;
                #pragma unroll
                for (int i = 0; i < 4; i++) {
                    int row = wave * 32 + i * 8 + (lane >> 3);
                    int cc  = (lane & 7) * 8;
                    half8 v = *(const half8*)&sC[row * 136 + hc * 64 + cc];
                    *(half8*)(base + row * 64 + cc) = v;
                }
            }
        } else {
            #pragma unroll
            for (int mi = 0; mi < 4; mi++)
                #pragma unroll
                for (int ni = 0; ni < 4; ni++) {
                    int row0 = wm*64 + mi*16 + l4*4;
                    int col  = wn*64 + ni*16 + l15;
                    half4v pk;
                    #pragma unroll
                    for (int r = 0; r < 4; r++) pk[r] = (f16)acc[mi][ni][r];
                    *(half4v*)&sC[col * 136 + row0] = pk;
                }
            __syncthreads();
            #pragma unroll
            for (int i = 0; i < 8; i++) {
                int col = wave * 32 + i * 4 + (lane >> 4);
                int rc  = (lane & 15) * 8;
                half8 v = *(const half8*)&sC[col * 136 + rc];
                int head = h0 + (col >> 6), dd = col & 63;
                *(half8*)(vtbuf + ((size_t)(bb * 12 + head) * 64 + dd) * 1024 + mo + rc) = v;
            }
        }
    } else {
        #pragma unroll
        for (int mi = 0; mi < 4; mi++)
            #pragma unroll
            for (int ni = 0; ni < 4; ni++)
                #pragma unroll
                for (int r = 0; r < 4; r++) {
                    int gm = m0 + wm*64 + mi*16 + l4*4 + r;
                    int gn = n0 + wn*64 + ni*16 + l15;
                    out[(size_t)gm * 768 + gn] = acc[mi][ni][r] + bias[gn];
                }
    }
}

// ---------------- flash attention: 32x32 MFMA, 128 q/block, LDS-staged K/V (dbuf) ----------------
// grid (96 bh, 8 qblk): all q-blocks of a head land on one XCD (96%8==0) -> K/V L2-resident.
__global__ __launch_bounds__(256, 3)
void attn_kernel(const f16* __restrict__ qbuf, const f16* __restrict__ kbuf,
                 const f16* __restrict__ vtbuf, f16* __restrict__ obuf)
{
    __shared__ __align__(16) f16 Ks[2][4096];   // [buf][64 keys][64 d], XOR-swizzled content
    __shared__ __align__(16) f16 Vs[2][4096];   // [buf][64 d][64 keys], XOR-swizzled content
    __shared__ __align__(16) char sPall[4 * 4096];  // per-wave 32x64 f16 P tile (swizzled)
    const int tid = threadIdx.x;
    const int lane = tid & 63, wave = tid >> 6;
    char* sP = sPall + wave * 4096;
    const int bh = blockIdx.x;              // 0..95
    const int b = bh / 12, h = bh % 12;
    const int q0 = blockIdx.y * 128 + wave * 32;
    const int l31 = lane & 31, hi = lane >> 5;
    const int sw0 = (l31 & 7) << 4;

    const f16* Q  = qbuf  + (size_t)bh * 65536;
    const f16* Kp = kbuf  + (size_t)bh * 65536;
    const f16* Vt = vtbuf + (size_t)bh * 65536;

    // Q fragments (B-operand of swapped QK, 32x32x16): col=l31, k=hi*8+j per 16-chunk
    const f16 slh = (f16)(0.125f * 1.44269504089f);
    half8 aq[4];
    #pragma unroll
    for (int c = 0; c < 4; c++) {
        aq[c] = *(const half8*)&Q[(size_t)(q0 + l31) * 64 + c * 16 + hi * 8];
        #pragma unroll
        for (int j = 0; j < 8; j++) aq[c][j] *= slh;
    }

    // staging geometry (pre-swizzled source, linear LDS dest)
    const int srow8 = lane >> 3;
    const int c16   = (lane & 7) ^ srow8;

    f32x16 o0 = {}, o1 = {};
    float lrq = 0.f, mrq = 0.f;

    #define STAGE(buf, kv) do {                                                     \
        _Pragma("unroll")                                                           \
        for (int i = 0; i < 2; ++i) {                                               \
            int rbase = wave * 16 + i * 8;                                          \
            int rl = rbase + srow8;                                                 \
            gload_lds16(Kp + (size_t)((kv) + rl) * 64 + c16 * 8, &Ks[buf][rbase * 64]); \
            gload_lds16(Vt + (size_t)rl * 1024 + (kv) + c16 * 8, &Vs[buf][rbase * 64]); \
        }                                                                           \
    } while (0)

    STAGE(0, 0);
    __syncthreads();

    for (int t = 0; t < 16; ++t) {
        const int cur = t & 1;
        if (t < 15) STAGE(cur ^ 1, (t + 1) * 64);

        const char* Kb = (const char*)&Ks[cur][0];
        const char* Vb = (const char*)&Vs[cur][0];

        // swapped QK (32x32x16): st = S^T[key][q] - mrq, log2 domain
        f32x16 st0, st1;
        #pragma unroll
        for (int j = 0; j < 16; j++) { st0[j] = -mrq; st1[j] = -mrq; }
        #pragma unroll
        for (int c = 0; c < 4; c++) {
            int koff = (c * 32 + hi * 16) ^ sw0;
            half8 k0 = *(const half8*)(Kb + l31 * 128 + koff);
            half8 k1 = *(const half8*)(Kb + (32 + l31) * 128 + koff);
            st0 = MFMA32(k0, aq[c], st0);
            st1 = MFMA32(k1, aq[c], st1);
        }

        // relative row max (lane holds 32 keys for query l31; complement in lane^32)
        float m16 = st0[0];
        #pragma unroll
        for (int j = 1; j < 16; j++) m16 = fmaxf(m16, st0[j]);
        #pragma unroll
        for (int j = 0; j < 16; j++) m16 = fmaxf(m16, st1[j]);
        m16 = fmaxf(m16, __shfl_xor(m16, 32));

        // defer-max (T13)
        if (!__all(m16 <= 11.0f)) {
            float d = fmaxf(m16, 0.f);
            float alpha = exp2f(-d);
            mrq += d;
            #pragma unroll
            for (int j = 0; j < 16; j++) { st0[j] -= d; st1[j] -= d; }
            lrq *= alpha;
            #pragma unroll
            for (int reg = 0; reg < 16; reg++) {
                float a = __shfl(alpha, (reg & 3) + 8 * (reg >> 2) + 4 * hi);
                o0[reg] *= a; o1[reg] *= a;
            }
        }

        // P = exp2(st) -> f16 (packed) -> LDS; rs accumulated in-lane
        float rs = 0.f;
        #define PSTORE(stv, tile) do {                                              \
            _Pragma("unroll")                                                       \
            for (int g = 0; g < 4; g++) {                                           \
                float e0 = exp2f(stv[4*g+0]), e1 = exp2f(stv[4*g+1]);               \
                float e2 = exp2f(stv[4*g+2]), e3 = exp2f(stv[4*g+3]);               \
                rs += (e0 + e1) + (e2 + e3);                                        \
                uint2 u;                                                            \
                u.x = __builtin_bit_cast(unsigned int, __builtin_amdgcn_cvt_pkrtz(e0, e1)); \
                u.y = __builtin_bit_cast(unsigned int, __builtin_amdgcn_cvt_pkrtz(e2, e3)); \
                int byte = (l31 * 128 + ((tile) * 32 + g * 8 + hi * 4) * 2) ^ sw0;  \
                *(uint2*)(sP + byte) = u;                                           \
            }                                                                       \
        } while (0)
        PSTORE(st0, 0);
        PSTORE(st1, 1);
        #undef PSTORE
        rs += __shfl_xor(rs, 32);
        lrq += rs;

        // PV (32x32x16): A = P[q][key], B = V^T[key][d]
        #pragma unroll
        for (int kc = 0; kc < 4; kc++) {
            int koff = (kc * 32 + hi * 16) ^ sw0;
            half8 pa = *(const half8*)(sP + l31 * 128 + koff);
            half8 v0 = *(const half8*)(Vb + l31 * 128 + koff);
            half8 v1 = *(const half8*)(Vb + (32 + l31) * 128 + koff);
            o0 = MFMA32(pa, v0, o0);
            o1 = MFMA32(pa, v1, o1);
        }

        __syncthreads();   // drains vmcnt (staged tile ready) + guards buffer reuse
    }
    #undef STAGE

    // epilogue: redistribute 1/lrq (at q=l31) to O's reg-mapped rows
    float rq = 1.0f / lrq;
    f16* Op = obuf + (size_t)b * 1024 * 768 + h * 64;
    #pragma unroll
    for (int reg = 0; reg < 16; reg++) {
        int qrow = (reg & 3) + 8 * (reg >> 2) + 4 * hi;
        float inv = __shfl(rq, qrow);
        size_t base = (size_t)(q0 + qrow) * 768;
        Op[base + l31]      = (f16)(o0[reg] * inv);
        Op[base + 32 + l31] = (f16)(o1[reg] * inv);
    }
}

extern "C" void kernel_launch(void* const* d_in, const int* in_sizes, int n_in,
                              void* d_out, int out_size, void* d_ws, size_t ws_size,
                              hipStream_t stream) {
    const float* x      = (const float*)d_in[0];
    const float* w_qkv  = (const float*)d_in[1];
    const float* w_proj = (const float*)d_in[2];
    const float* b_proj = (const float*)d_in[3];
    float* out = (float*)d_out;
    char* ws = (char*)d_ws;

    f16* x_h      = (f16*)(ws + 0);
    f16* w_qkv_t  = (f16*)(ws + 12582912);
    f16* w_proj_t = (f16*)(ws + 16121856);
    f16* qb       = (f16*)(ws + 17301504);
    f16* kb       = (f16*)(ws + 29884416);
    f16* vtb      = (f16*)(ws + 42467328);
    f16* ob       = (f16*)(ws + 55050240);

    cast_f32_to_f16<<<dim3(6144), dim3(256), 0, stream>>>(x, x_h, 6291456 / 4);
    transpose_cast<<<dim3(2304 / 32, 768 / 32), dim3(256), 0, stream>>>(w_qkv, w_qkv_t, 768, 2304);
    transpose_cast<<<dim3(768 / 32, 768 / 32), dim3(256), 0, stream>>>(w_proj, w_proj_t, 768, 768);
    gemm_bt<0><<<dim3(18 * 64), dim3(256), 0, stream>>>(
        x_h, w_qkv_t, qb, kb, vtb, nullptr, nullptr);
    attn_kernel<<<dim3(96, 8), dim3(256), 0, stream>>>(qb, kb, vtb, ob);
    gemm_bt<1><<<dim3(6 * 64), dim3(256), 0, stream>>>(
        ob, w_proj_t, nullptr, nullptr, nullptr, out, b_proj);
}